// Round 1
// baseline (1131.257 us; speedup 1.0000x reference)
//
#include <hip/hip_runtime.h>
#include <cstdint>
#include <cstddef>

#define EPSV 1e-5f

// Problem constants
// N=4, C=128, G=8, P=9, GC=16, H=W=96; x1: 256ch 48x48; x2: 64ch 192x192
#define NPIX 9216          // 96*96
#define MTOT 36864         // 4*96*96

__device__ __forceinline__ float silu_f(float v) { return v / (1.f + __expf(-v)); }

// ---------------------------------------------------------------------------
// Weight prep: fold BN into conv weights, transpose everything to [ci][co]
// WTS layout (floats):
//   0      W1r   [256][128]  (conv_w * s)
//   32768  b1    [128]
//   32896  W1br  [64][128]
//   41088  b1b   [128]
//   41216  W2r   [9][128][128]  (k-major)
//   188672 b2    [128]
//   188800 Wip   [128][128]
//   205184 Wom   [128][216]  (off 144 | m 72)
//   232832 Wop   [128][128]
//   249216 bom   [216]
// total 249432
// ---------------------------------------------------------------------------
__global__ __launch_bounds__(256) void prep_kernel(
    const float* __restrict__ conv_w, const float* __restrict__ conv_g,
    const float* __restrict__ conv_b, const float* __restrict__ conv_rm, const float* __restrict__ conv_rv,
    const float* __restrict__ conv1_w, const float* __restrict__ conv1_g,
    const float* __restrict__ conv1_b, const float* __restrict__ conv1_rm, const float* __restrict__ conv1_rv,
    const float* __restrict__ conv2_w, const float* __restrict__ conv2_g,
    const float* __restrict__ conv2_bb, const float* __restrict__ conv2_rm, const float* __restrict__ conv2_rv,
    const float* __restrict__ ip_w, const float* __restrict__ op_w,
    const float* __restrict__ off_w, const float* __restrict__ m_w,
    const float* __restrict__ off_b, const float* __restrict__ m_b,
    float* __restrict__ WTS)
{
  int idx = blockIdx.x * 256 + threadIdx.x;
  if (idx < 32768) {
    int ci = idx >> 7, co = idx & 127;
    float s = conv_g[co] * rsqrtf(conv_rv[co] + EPSV);
    WTS[idx] = conv_w[co * 256 + ci] * s;
  } else if (idx < 32896) {
    int co = idx - 32768;
    float s = conv_g[co] * rsqrtf(conv_rv[co] + EPSV);
    WTS[idx] = conv_b[co] - conv_rm[co] * s;
  } else if (idx < 41088) {
    int r = idx - 32896; int ci = r >> 7, co = r & 127;
    float s = conv1_g[co] * rsqrtf(conv1_rv[co] + EPSV);
    WTS[idx] = conv1_w[co * 64 + ci] * s;
  } else if (idx < 41216) {
    int co = idx - 41088;
    float s = conv1_g[co] * rsqrtf(conv1_rv[co] + EPSV);
    WTS[idx] = conv1_b[co] - conv1_rm[co] * s;
  } else if (idx < 188672) {
    int r = idx - 41216; int k = r >> 14; int ci = (r >> 7) & 127; int co = r & 127;
    float s = conv2_g[co] * rsqrtf(conv2_rv[co] + EPSV);
    WTS[idx] = conv2_w[(co * 128 + ci) * 9 + k] * s;
  } else if (idx < 188800) {
    int co = idx - 188672;
    float s = conv2_g[co] * rsqrtf(conv2_rv[co] + EPSV);
    WTS[idx] = conv2_bb[co] - conv2_rm[co] * s;
  } else if (idx < 205184) {
    int r = idx - 188800; int ci = r >> 7, co = r & 127;
    WTS[idx] = ip_w[co * 128 + ci];
  } else if (idx < 232832) {
    int r = idx - 205184; int ci = r / 216, col = r % 216;
    WTS[idx] = (col < 144) ? off_w[col * 128 + ci] : m_w[(col - 144) * 128 + ci];
  } else if (idx < 249216) {
    int r = idx - 232832; int ci = r >> 7, co = r & 127;
    WTS[idx] = op_w[co * 128 + ci];
  } else if (idx < 249432) {
    int col = idx - 249216;
    WTS[idx] = (col < 144) ? off_b[col] : m_b[col - 144];
  }
}

// ---------------------------------------------------------------------------
// conv1x1 + folded BN + SiLU: NCHW input -> NHWC output (C_out=128)
// block 256, Mtile=32 pixels, K chunked by 64. LDS 40KB.
// ---------------------------------------------------------------------------
__global__ __launch_bounds__(256) void conv1x1_kernel(
    const float* __restrict__ x, const float* __restrict__ Wm,
    const float* __restrict__ bias, int K, int HW, float* __restrict__ out)
{
  __shared__ float As[64 * 32];    // [ci][px]
  __shared__ float Bs[64 * 128];   // [ci][co]
  int tilesPerImg = HW >> 5;
  int n = blockIdx.x / tilesPerImg;
  int hw0 = (blockIdx.x % tilesPerImg) << 5;
  const float* xn = x + (size_t)n * K * HW;
  int t = threadIdx.x;
  int co4 = (t & 31) << 2;
  int px4 = (t >> 5) << 2;
  float acc[4][4];
#pragma unroll
  for (int i = 0; i < 4; ++i)
#pragma unroll
    for (int j = 0; j < 4; ++j) acc[i][j] = 0.f;

  for (int k0 = 0; k0 < K; k0 += 64) {
    if (k0) __syncthreads();
    for (int i = t; i < 64 * 32; i += 256) {
      int ci = i >> 5, px = i & 31;
      As[i] = xn[(size_t)(k0 + ci) * HW + hw0 + px];
    }
    for (int i = t; i < 64 * 128; i += 256) {
      int ci = i >> 7, co = i & 127;
      Bs[i] = Wm[(size_t)(k0 + ci) * 128 + co];
    }
    __syncthreads();
#pragma unroll 4
    for (int c = 0; c < 64; ++c) {
      float4 a = *(const float4*)&As[c * 32 + px4];
      float4 b = *(const float4*)&Bs[c * 128 + co4];
      acc[0][0] += a.x * b.x; acc[0][1] += a.x * b.y; acc[0][2] += a.x * b.z; acc[0][3] += a.x * b.w;
      acc[1][0] += a.y * b.x; acc[1][1] += a.y * b.y; acc[1][2] += a.y * b.z; acc[1][3] += a.y * b.w;
      acc[2][0] += a.z * b.x; acc[2][1] += a.z * b.y; acc[2][2] += a.z * b.z; acc[2][3] += a.z * b.w;
      acc[3][0] += a.w * b.x; acc[3][1] += a.w * b.y; acc[3][2] += a.w * b.z; acc[3][3] += a.w * b.w;
    }
  }
  float4 bb = *(const float4*)&bias[co4];
#pragma unroll
  for (int i = 0; i < 4; ++i) {
    float4 v;
    v.x = silu_f(acc[i][0] + bb.x);
    v.y = silu_f(acc[i][1] + bb.y);
    v.z = silu_f(acc[i][2] + bb.z);
    v.w = silu_f(acc[i][3] + bb.w);
    *(float4*)&out[((size_t)(n * HW) + hw0 + px4 + i) * 128 + co4] = v;
  }
}

// ---------------------------------------------------------------------------
// jax.image.resize bilinear 2x upsample (half-pixel, edge-normalized == clamped)
// y1 NHWC (4,48,48,128) -> feat1 NHWC (4,96,96,128)
// ---------------------------------------------------------------------------
__global__ __launch_bounds__(256) void upsample_kernel(
    const float* __restrict__ y1, float* __restrict__ feat1)
{
  int idx = blockIdx.x * 256 + threadIdx.x;   // 4718592 total
  int c = idx & 127;
  int pw = idx >> 7;
  int ow = pw % 96; int t1 = pw / 96;
  int oh = t1 % 96; int n = t1 / 96;
  float sh = oh * 0.5f - 0.25f, sw = ow * 0.5f - 0.25f;
  float hf = floorf(sh), wf = floorf(sw);
  float fy = sh - hf, fx = sw - wf;
  int h0 = (int)hf, w0 = (int)wf;
  int h0c = max(h0, 0), h1c = min(h0 + 1, 47);
  int w0c = max(w0, 0), w1c = min(w0 + 1, 47);
  const float* yn = y1 + (size_t)n * 48 * 48 * 128 + c;
  float v00 = yn[(h0c * 48 + w0c) * 128];
  float v01 = yn[(h0c * 48 + w1c) * 128];
  float v10 = yn[(h1c * 48 + w0c) * 128];
  float v11 = yn[(h1c * 48 + w1c) * 128];
  feat1[idx] = (1.f - fy) * ((1.f - fx) * v00 + fx * v01) + fy * ((1.f - fx) * v10 + fx * v11);
}

// ---------------------------------------------------------------------------
// 3x3 s2 p1 conv + folded BN + SiLU: y2 NHWC (4,192,192,128) -> feat2 NHWC (4,96,96,128)
// block 256, Mtile = 32 output px (one row segment), LDS 48KB, 9 kpos x 2 K-chunks
// ---------------------------------------------------------------------------
__global__ __launch_bounds__(256) void conv2_kernel(
    const float* __restrict__ y2, const float* __restrict__ W2r,
    const float* __restrict__ b2, float* __restrict__ feat2)
{
  __shared__ float As[32 * 128];   // [px][ci]
  __shared__ float Bs[64 * 128];   // [ci][co]
  int bid = blockIdx.x;            // n*288 + tile
  int n = bid / 288; int tile = bid % 288;
  int oh = tile / 3; int ow0 = (tile % 3) << 5;
  int t = threadIdx.x;
  int co4 = (t & 31) << 2;
  int px4 = (t >> 5) << 2;
  int ci = t & 127; int p0 = t >> 7;
  float acc[4][4];
#pragma unroll
  for (int i = 0; i < 4; ++i)
#pragma unroll
    for (int j = 0; j < 4; ++j) acc[i][j] = 0.f;
  const float* y2n = y2 + (size_t)n * 192 * 192 * 128;

  for (int kh = 0; kh < 3; ++kh) {
    int ih = 2 * oh - 1 + kh;
    bool hok = ((unsigned)ih < 192u);
    for (int kw = 0; kw < 3; ++kw) {
      __syncthreads();   // previous compute done before overwriting As/Bs
      // stage A: 32 px x 128 ci (stride-2 input cols, bounds -> 0)
#pragma unroll
      for (int i = 0; i < 16; ++i) {
        int px = p0 + i * 2;
        int iw = ((ow0 + px) << 1) - 1 + kw;
        float v = 0.f;
        if (hok && (unsigned)iw < 192u) v = y2n[((size_t)ih * 192 + iw) * 128 + ci];
        As[px * 128 + ci] = v;
      }
      const float* Bk = W2r + (kh * 3 + kw) * 16384;
      for (int kc = 0; kc < 2; ++kc) {
        if (kc) __syncthreads();
        for (int i = t; i < 8192; i += 256) Bs[i] = Bk[kc * 8192 + i];
        __syncthreads();
        int kbase = kc * 64;
#pragma unroll 4
        for (int c = 0; c < 64; ++c) {
          float4 b = *(const float4*)&Bs[c * 128 + co4];
          float a0 = As[(px4 + 0) * 128 + kbase + c];
          float a1 = As[(px4 + 1) * 128 + kbase + c];
          float a2 = As[(px4 + 2) * 128 + kbase + c];
          float a3 = As[(px4 + 3) * 128 + kbase + c];
          acc[0][0] += a0 * b.x; acc[0][1] += a0 * b.y; acc[0][2] += a0 * b.z; acc[0][3] += a0 * b.w;
          acc[1][0] += a1 * b.x; acc[1][1] += a1 * b.y; acc[1][2] += a1 * b.z; acc[1][3] += a1 * b.w;
          acc[2][0] += a2 * b.x; acc[2][1] += a2 * b.y; acc[2][2] += a2 * b.z; acc[2][3] += a2 * b.w;
          acc[3][0] += a3 * b.x; acc[3][1] += a3 * b.y; acc[3][2] += a3 * b.z; acc[3][3] += a3 * b.w;
        }
      }
    }
  }
  float4 bb = *(const float4*)&b2[co4];
#pragma unroll
  for (int i = 0; i < 4; ++i) {
    float4 v;
    v.x = silu_f(acc[i][0] + bb.x);
    v.y = silu_f(acc[i][1] + bb.y);
    v.z = silu_f(acc[i][2] + bb.z);
    v.w = silu_f(acc[i][3] + bb.w);
    *(float4*)&feat2[((size_t)n * NPIX + oh * 96 + ow0 + px4 + i) * 128 + co4] = v;
  }
}

// ---------------------------------------------------------------------------
// Generic NHWC GEMM: out[M][Nc] = act(A[M][128] @ B[128][Nc] + bias)
// store_mode 0: row-major [M][Nc]; 1: NCHW into d_out with channel offset + ReLU
// block 256, Mtile 32, Ntile 128 (blockIdx.y), K chunked by 64. LDS 48KB.
// ---------------------------------------------------------------------------
__global__ __launch_bounds__(256) void gemm_kernel(
    const float* __restrict__ A, const float* __restrict__ B,
    const float* __restrict__ bias, int Nc, int act, int store_mode, int choff,
    float* __restrict__ out)
{
  __shared__ float As[32 * 128];
  __shared__ float Bs[64 * 128];
  int m0 = blockIdx.x << 5;
  int n0 = blockIdx.y << 7;
  int t = threadIdx.x;
  for (int i = t; i < 4096; i += 256) As[i] = A[(size_t)m0 * 128 + i];
  int co4 = (t & 31) << 2;
  int px4 = (t >> 5) << 2;
  float acc[4][4];
#pragma unroll
  for (int i = 0; i < 4; ++i)
#pragma unroll
    for (int j = 0; j < 4; ++j) acc[i][j] = 0.f;

  for (int k0 = 0; k0 < 128; k0 += 64) {
    if (k0) __syncthreads();
    for (int i = t; i < 8192; i += 256) {
      int kk = i >> 7; int col = n0 + (i & 127);
      Bs[i] = (col < Nc) ? B[(size_t)(k0 + kk) * Nc + col] : 0.f;
    }
    __syncthreads();
#pragma unroll 4
    for (int c = 0; c < 64; ++c) {
      float4 b = *(const float4*)&Bs[c * 128 + co4];
      float a0 = As[(px4 + 0) * 128 + k0 + c];
      float a1 = As[(px4 + 1) * 128 + k0 + c];
      float a2 = As[(px4 + 2) * 128 + k0 + c];
      float a3 = As[(px4 + 3) * 128 + k0 + c];
      acc[0][0] += a0 * b.x; acc[0][1] += a0 * b.y; acc[0][2] += a0 * b.z; acc[0][3] += a0 * b.w;
      acc[1][0] += a1 * b.x; acc[1][1] += a1 * b.y; acc[1][2] += a1 * b.z; acc[1][3] += a1 * b.w;
      acc[2][0] += a2 * b.x; acc[2][1] += a2 * b.y; acc[2][2] += a2 * b.z; acc[2][3] += a2 * b.w;
      acc[3][0] += a3 * b.x; acc[3][1] += a3 * b.y; acc[3][2] += a3 * b.z; acc[3][3] += a3 * b.w;
    }
  }
#pragma unroll
  for (int i = 0; i < 4; ++i) {
    int m = m0 + px4 + i;
#pragma unroll
    for (int j = 0; j < 4; ++j) {
      int col = n0 + co4 + j;
      if (col >= Nc) continue;
      float v = acc[i][j] + bias[col];
      if (act == 1) v = fmaxf(v, 0.f);
      if (store_mode == 0) {
        out[(size_t)m * Nc + col] = v;
      } else {
        int nn = m / NPIX; int hw = m - nn * NPIX;
        out[((size_t)(nn * 384 + choff + col)) * NPIX + hw] = v;
      }
    }
  }
}

// ---------------------------------------------------------------------------
// Depthwise 3x3 conv + bias + LayerNorm + GELU(tanh) : feat NHWC -> dwg [M][128]
// block 128 = one pixel's channels
// ---------------------------------------------------------------------------
__global__ __launch_bounds__(128) void dwln_kernel(
    const float* __restrict__ feat, const float* __restrict__ dw_w,
    const float* __restrict__ dw_b, const float* __restrict__ ln_g,
    const float* __restrict__ ln_b, float* __restrict__ dwg)
{
  int pixel = blockIdx.x;
  int n = pixel / NPIX; int hw = pixel - n * NPIX;
  int h = hw / 96; int w = hw - h * 96;
  int c = threadIdx.x;
  const float* fn = feat + (size_t)n * NPIX * 128 + c;
  float acc = dw_b[c];
#pragma unroll
  for (int kh = 0; kh < 3; ++kh) {
    int hh = h + kh - 1;
    if ((unsigned)hh >= 96u) continue;
#pragma unroll
    for (int kw = 0; kw < 3; ++kw) {
      int ww = w + kw - 1;
      if ((unsigned)ww >= 96u) continue;
      acc += fn[(hh * 96 + ww) * 128] * dw_w[(kh * 3 + kw) * 128 + c];
    }
  }
  __shared__ float rs[128], rq[128];
  rs[c] = acc; rq[c] = acc * acc;
  __syncthreads();
  for (int off = 64; off > 0; off >>= 1) {
    if (c < off) { rs[c] += rs[c + off]; rq[c] += rq[c + off]; }
    __syncthreads();
  }
  float mean = rs[0] * (1.f / 128.f);
  float var = rq[0] * (1.f / 128.f) - mean * mean;
  float xn = (acc - mean) * rsqrtf(var + EPSV) * ln_g[c] + ln_b[c];
  float z = 0.7978845608028654f * (xn + 0.044715f * xn * xn * xn);
  float th;
  if (z > 15.f) th = 1.f;
  else if (z < -15.f) th = -1.f;
  else { float e = __expf(2.f * z); th = (e - 1.f) / (e + 1.f); }
  dwg[(size_t)pixel * 128 + c] = 0.5f * xn * (1.f + th);
}

// ---------------------------------------------------------------------------
// Deformable sampling: per (pixel,g): softmax(m), 9 bilinear taps over xp groups
// block 256 = 2 px x 8 g x 16 c ; grid M/2
// ---------------------------------------------------------------------------
__global__ __launch_bounds__(256) void sample_kernel(
    const float* __restrict__ xp, const float* __restrict__ offm,
    float* __restrict__ vagg)
{
  __shared__ float S[432];
  int t = threadIdx.x;
  int bid = blockIdx.x;
  for (int i = t; i < 432; i += 256) S[i] = offm[(size_t)bid * 432 + i];
  __syncthreads();
  int pxl = t >> 7;
  int g = (t >> 4) & 7;
  int c = t & 15;
  int pixel = bid * 2 + pxl;
  int n = pixel / NPIX; int hw = pixel - n * NPIX;
  int h = hw / 96; int w = hw - h * 96;
  const float* Sp = S + pxl * 216;
  float lg[9]; float mx = -1e30f;
#pragma unroll
  for (int p = 0; p < 9; ++p) { lg[p] = Sp[144 + g * 9 + p]; mx = fmaxf(mx, lg[p]); }
  float se = 0.f;
#pragma unroll
  for (int p = 0; p < 9; ++p) { lg[p] = __expf(lg[p] - mx); se += lg[p]; }
  float inv = 1.f / se;
  const float* xpn = xp + (size_t)n * NPIX * 128 + g * 16 + c;
  float acc = 0.f;
#pragma unroll
  for (int p = 0; p < 9; ++p) {
    float dx = Sp[g * 18 + p * 2], dy = Sp[g * 18 + p * 2 + 1];
    float pyu = (float)(h + p / 3 - 1) + dy;   // unpadded coords (pad shift cancels)
    float pxu = (float)(w + p % 3 - 1) + dx;
    float yf = floorf(pyu), xf = floorf(pxu);
    float wy = pyu - yf, wx = pxu - xf;
    int y0 = (int)yf, x0 = (int)xf;
    float w00 = (1.f - wy) * (1.f - wx), w01 = (1.f - wy) * wx;
    float w10 = wy * (1.f - wx), w11 = wy * wx;
    float v = 0.f;
    if ((unsigned)y0 < 96u) {
      if ((unsigned)x0 < 96u)       v += w00 * xpn[(y0 * 96 + x0) * 128];
      if ((unsigned)(x0 + 1) < 96u) v += w01 * xpn[(y0 * 96 + x0 + 1) * 128];
    }
    if ((unsigned)(y0 + 1) < 96u) {
      if ((unsigned)x0 < 96u)       v += w10 * xpn[((y0 + 1) * 96 + x0) * 128];
      if ((unsigned)(x0 + 1) < 96u) v += w11 * xpn[((y0 + 1) * 96 + x0 + 1) * 128];
    }
    acc += lg[p] * inv * v;
  }
  vagg[(size_t)pixel * 128 + g * 16 + c] = acc;
}

// ---------------------------------------------------------------------------
// x0 passthrough into out channels [128,256)
// ---------------------------------------------------------------------------
__global__ __launch_bounds__(256) void copy_x0_kernel(
    const float4* __restrict__ x0, float4* __restrict__ out)
{
  int idx = blockIdx.x * 256 + threadIdx.x;   // 1179648 total (float4 units)
  int n = idx / (128 * 2304);
  int r = idx - n * (128 * 2304);
  out[(size_t)(n * 384 + 128) * 2304 + r] = x0[(size_t)n * 128 * 2304 + r];
}

// ---------------------------------------------------------------------------
extern "C" void kernel_launch(void* const* d_in, const int* in_sizes, int n_in,
                              void* d_out, int out_size, void* d_ws, size_t ws_size,
                              hipStream_t stream)
{
  (void)in_sizes; (void)n_in; (void)out_size; (void)ws_size;
  const float* x0      = (const float*)d_in[0];
  const float* x1      = (const float*)d_in[1];
  const float* x2      = (const float*)d_in[2];
  const float* conv_w  = (const float*)d_in[3];
  const float* conv_g  = (const float*)d_in[4];
  const float* conv_b  = (const float*)d_in[5];
  const float* conv_rm = (const float*)d_in[6];
  const float* conv_rv = (const float*)d_in[7];
  const float* conv1_w = (const float*)d_in[8];
  const float* conv1_g = (const float*)d_in[9];
  const float* conv1_b = (const float*)d_in[10];
  const float* conv1_rm= (const float*)d_in[11];
  const float* conv1_rv= (const float*)d_in[12];
  const float* conv2_w = (const float*)d_in[13];
  const float* conv2_g = (const float*)d_in[14];
  const float* conv2_b = (const float*)d_in[15];
  const float* conv2_rm= (const float*)d_in[16];
  const float* conv2_rv= (const float*)d_in[17];
  const float* dw_w    = (const float*)d_in[18];
  const float* dw_b    = (const float*)d_in[19];
  const float* ln_g    = (const float*)d_in[20];
  const float* ln_b    = (const float*)d_in[21];
  const float* off_w   = (const float*)d_in[22];
  const float* off_b   = (const float*)d_in[23];
  const float* m_w     = (const float*)d_in[24];
  const float* m_b     = (const float*)d_in[25];
  const float* ip_w    = (const float*)d_in[26];
  const float* ip_b    = (const float*)d_in[27];
  const float* op_w    = (const float*)d_in[28];
  const float* op_b    = (const float*)d_in[29];
  float* out = (float*)d_out;
  float* ws = (float*)d_ws;

  // workspace layout (floats)
  float* feat1 = ws;                       // 4,718,592
  float* feat2 = ws + 4718592;             // 4,718,592 (y1 aliases its start pre-conv2)
  float* y1    = feat2;                    // 1,179,648 — dead before feat2 is written
  float* R     = ws + 9437184;             // 22,118,400 region
  float* y2    = R;                        // 18,874,368 (dead after conv2)
  float* xp    = R;                        // 4,718,592
  float* dwg   = R + 4718592;              // 4,718,592
  float* offm  = R + 9437184;              // 7,962,624
  float* vagg  = R + 17399808;             // 4,718,592
  float* WTS   = ws + 31555584;            // 249,432

  float* W1r  = WTS;
  float* b1   = WTS + 32768;
  float* W1br = WTS + 32896;
  float* b1b  = WTS + 41088;
  float* W2r  = WTS + 41216;
  float* b2   = WTS + 188672;
  float* Wip  = WTS + 188800;
  float* Wom  = WTS + 205184;
  float* Wop  = WTS + 232832;
  float* bom  = WTS + 249216;

  prep_kernel<<<975, 256, 0, stream>>>(
      conv_w, conv_g, conv_b, conv_rm, conv_rv,
      conv1_w, conv1_g, conv1_b, conv1_rm, conv1_rv,
      conv2_w, conv2_g, conv2_b, conv2_rm, conv2_rv,
      ip_w, op_w, off_w, m_w, off_b, m_b, WTS);

  // x1 path: 1x1 conv (K=256) on 48x48 -> y1 NHWC; upsample -> feat1
  conv1x1_kernel<<<288, 256, 0, stream>>>(x1, W1r, b1, 256, 2304, y1);
  upsample_kernel<<<18432, 256, 0, stream>>>(y1, feat1);

  // x2 path: 1x1 conv (K=64) on 192x192 -> y2 NHWC; 3x3 s2 conv -> feat2
  conv1x1_kernel<<<4608, 256, 0, stream>>>(x2, W1br, b1b, 64, 36864, y2);
  conv2_kernel<<<1152, 256, 0, stream>>>(y2, W2r, b2, feat2);

  for (int d = 0; d < 2; ++d) {
    const float* feat = d ? feat2 : feat1;
    int choff = d ? 256 : 0;
    gemm_kernel<<<dim3(1152, 1), 256, 0, stream>>>(feat, Wip, ip_b, 128, 0, 0, 0, xp);
    dwln_kernel<<<36864, 128, 0, stream>>>(feat, dw_w, dw_b, ln_g, ln_b, dwg);
    gemm_kernel<<<dim3(1152, 2), 256, 0, stream>>>(dwg, Wom, bom, 216, 0, 0, 0, offm);
    sample_kernel<<<18432, 256, 0, stream>>>(xp, offm, vagg);
    gemm_kernel<<<dim3(1152, 1), 256, 0, stream>>>(vagg, Wop, op_b, 128, 1, 1, choff, out);
  }

  copy_x0_kernel<<<4608, 256, 0, stream>>>((const float4*)x0, (float4*)out);
}

// Round 2
// 690.783 us; speedup vs baseline: 1.6376x; 1.6376x over previous
//
#include <hip/hip_runtime.h>
#include <cstdint>
#include <cstddef>

#define EPSV 1e-5f
#define NPIX 9216          // 96*96
#define MTOT 36864         // 4*96*96
#define LDA 136            // padded bf16 k-stride (128 + 8) -> breaks bank conflicts

typedef __bf16 bf16;
typedef __attribute__((ext_vector_type(8))) __bf16 bf16x8;
typedef __attribute__((ext_vector_type(4))) __bf16 bf16x4;
typedef __attribute__((ext_vector_type(4))) float  f32x4;

__device__ __forceinline__ float silu_f(float v) { return v / (1.f + __expf(-v)); }

// ---------------------------------------------------------------------------
// WTSf (float) layout:
//   0      W1r  [256][128]   (conv_w * s, [ci][co])
//   32768  b1   [128]
//   32896  W1br [64][128]
//   41088  b1b  [128]
//   41216  b2   [128]
//   41344  bom  [224]  (off 144 | m 72 | pad 8 zeros)
//   total 41568 floats
// WTSb (bf16) layout — all [co][ci] for MFMA B-operand:
//   0       W2b  [9][128][128]  (BN-folded)
//   147456  Wipb [128][128]
//   163840  Womb [224][128]  (rows 216..223 zero)
//   192512  Wopb [128][128]
//   total 208896 bf16
// ---------------------------------------------------------------------------
__global__ __launch_bounds__(256) void prep_kernel(
    const float* __restrict__ conv_w, const float* __restrict__ conv_g,
    const float* __restrict__ conv_b, const float* __restrict__ conv_rm, const float* __restrict__ conv_rv,
    const float* __restrict__ conv1_w, const float* __restrict__ conv1_g,
    const float* __restrict__ conv1_b, const float* __restrict__ conv1_rm, const float* __restrict__ conv1_rv,
    const float* __restrict__ conv2_w, const float* __restrict__ conv2_g,
    const float* __restrict__ conv2_bb, const float* __restrict__ conv2_rm, const float* __restrict__ conv2_rv,
    const float* __restrict__ ip_w, const float* __restrict__ op_w,
    const float* __restrict__ off_w, const float* __restrict__ m_w,
    const float* __restrict__ off_b, const float* __restrict__ m_b,
    float* __restrict__ WTSf, bf16* __restrict__ WTSb)
{
  int idx = blockIdx.x * 256 + threadIdx.x;
  if (idx < 41568) {
    if (idx < 32768) {
      int ci = idx >> 7, co = idx & 127;
      float s = conv_g[co] * rsqrtf(conv_rv[co] + EPSV);
      WTSf[idx] = conv_w[co * 256 + ci] * s;
    } else if (idx < 32896) {
      int co = idx - 32768;
      float s = conv_g[co] * rsqrtf(conv_rv[co] + EPSV);
      WTSf[idx] = conv_b[co] - conv_rm[co] * s;
    } else if (idx < 41088) {
      int r = idx - 32896; int ci = r >> 7, co = r & 127;
      float s = conv1_g[co] * rsqrtf(conv1_rv[co] + EPSV);
      WTSf[idx] = conv1_w[co * 64 + ci] * s;
    } else if (idx < 41216) {
      int co = idx - 41088;
      float s = conv1_g[co] * rsqrtf(conv1_rv[co] + EPSV);
      WTSf[idx] = conv1_b[co] - conv1_rm[co] * s;
    } else if (idx < 41344) {
      int co = idx - 41216;
      float s = conv2_g[co] * rsqrtf(conv2_rv[co] + EPSV);
      WTSf[idx] = conv2_bb[co] - conv2_rm[co] * s;
    } else {
      int col = idx - 41344;
      WTSf[idx] = (col < 144) ? off_b[col] : (col < 216 ? m_b[col - 144] : 0.f);
    }
  } else {
    int j = idx - 41568;
    if (j < 147456) {
      int kp = j >> 14; int r = j & 16383; int co = r >> 7, ci = r & 127;
      float s = conv2_g[co] * rsqrtf(conv2_rv[co] + EPSV);
      WTSb[j] = (bf16)(conv2_w[(co * 128 + ci) * 9 + kp] * s);
    } else if (j < 163840) {
      int r = j - 147456; int co = r >> 7, ci = r & 127;
      WTSb[j] = (bf16)ip_w[co * 128 + ci];
    } else if (j < 192512) {
      int r = j - 163840; int co = r >> 7, ci = r & 127;
      float v = (co < 144) ? off_w[co * 128 + ci] : (co < 216 ? m_w[(co - 144) * 128 + ci] : 0.f);
      WTSb[j] = (bf16)v;
    } else if (j < 208896) {
      int r = j - 192512; int co = r >> 7, ci = r & 127;
      WTSb[j] = (bf16)op_w[co * 128 + ci];
    }
  }
}

// ---------------------------------------------------------------------------
// conv1x1 + folded BN + SiLU: NCHW input -> NHWC output (C_out=128), fp32 FMA
// ---------------------------------------------------------------------------
__global__ __launch_bounds__(256) void conv1x1_kernel(
    const float* __restrict__ x, const float* __restrict__ Wm,
    const float* __restrict__ bias, int K, int HW, float* __restrict__ out)
{
  __shared__ float As[64 * 32];    // [ci][px]
  __shared__ float Bs[64 * 128];   // [ci][co]
  int tilesPerImg = HW >> 5;
  int n = blockIdx.x / tilesPerImg;
  int hw0 = (blockIdx.x % tilesPerImg) << 5;
  const float* xn = x + (size_t)n * K * HW;
  int t = threadIdx.x;
  int co4 = (t & 31) << 2;
  int px4 = (t >> 5) << 2;
  float acc[4][4];
#pragma unroll
  for (int i = 0; i < 4; ++i)
#pragma unroll
    for (int j = 0; j < 4; ++j) acc[i][j] = 0.f;

  for (int k0 = 0; k0 < K; k0 += 64) {
    if (k0) __syncthreads();
    for (int i = t; i < 64 * 32; i += 256) {
      int ci = i >> 5, px = i & 31;
      As[i] = xn[(size_t)(k0 + ci) * HW + hw0 + px];
    }
    for (int i = t; i < 64 * 128; i += 256) {
      int ci = i >> 7, co = i & 127;
      Bs[i] = Wm[(size_t)(k0 + ci) * 128 + co];
    }
    __syncthreads();
#pragma unroll 4
    for (int c = 0; c < 64; ++c) {
      float4 a = *(const float4*)&As[c * 32 + px4];
      float4 b = *(const float4*)&Bs[c * 128 + co4];
      acc[0][0] += a.x * b.x; acc[0][1] += a.x * b.y; acc[0][2] += a.x * b.z; acc[0][3] += a.x * b.w;
      acc[1][0] += a.y * b.x; acc[1][1] += a.y * b.y; acc[1][2] += a.y * b.z; acc[1][3] += a.y * b.w;
      acc[2][0] += a.z * b.x; acc[2][1] += a.z * b.y; acc[2][2] += a.z * b.z; acc[2][3] += a.z * b.w;
      acc[3][0] += a.w * b.x; acc[3][1] += a.w * b.y; acc[3][2] += a.w * b.z; acc[3][3] += a.w * b.w;
    }
  }
  float4 bb = *(const float4*)&bias[co4];
#pragma unroll
  for (int i = 0; i < 4; ++i) {
    float4 v;
    v.x = silu_f(acc[i][0] + bb.x);
    v.y = silu_f(acc[i][1] + bb.y);
    v.z = silu_f(acc[i][2] + bb.z);
    v.w = silu_f(acc[i][3] + bb.w);
    *(float4*)&out[((size_t)(n * HW) + hw0 + px4 + i) * 128 + co4] = v;
  }
}

// ---------------------------------------------------------------------------
// bilinear 2x upsample, NHWC
// ---------------------------------------------------------------------------
__global__ __launch_bounds__(256) void upsample_kernel(
    const float* __restrict__ y1, float* __restrict__ feat1)
{
  int idx = blockIdx.x * 256 + threadIdx.x;
  int c = idx & 127;
  int pw = idx >> 7;
  int ow = pw % 96; int t1 = pw / 96;
  int oh = t1 % 96; int n = t1 / 96;
  float sh = oh * 0.5f - 0.25f, sw = ow * 0.5f - 0.25f;
  float hf = floorf(sh), wf = floorf(sw);
  float fy = sh - hf, fx = sw - wf;
  int h0 = (int)hf, w0 = (int)wf;
  int h0c = max(h0, 0), h1c = min(h0 + 1, 47);
  int w0c = max(w0, 0), w1c = min(w0 + 1, 47);
  const float* yn = y1 + (size_t)n * 48 * 48 * 128 + c;
  float v00 = yn[(h0c * 48 + w0c) * 128];
  float v01 = yn[(h0c * 48 + w1c) * 128];
  float v10 = yn[(h1c * 48 + w0c) * 128];
  float v11 = yn[(h1c * 48 + w1c) * 128];
  feat1[idx] = (1.f - fy) * ((1.f - fx) * v00 + fx * v01) + fy * ((1.f - fx) * v10 + fx * v11);
}

// ---------------------------------------------------------------------------
// conv2 via MFMA: 3x3 s2 p1 + BN + SiLU. y2 NHWC fp32 -> feat2 NHWC fp32.
// Block 256 = 4 waves. Tile: 64 output px (flattened) x 128 co.
// K loop: 9 kpos x (128 ci = 4 mfma k-steps). LDS: A 64xLDA bf16, B 128xLDA bf16.
// ---------------------------------------------------------------------------
__global__ __launch_bounds__(256) void conv2_mfma_kernel(
    const float* __restrict__ y2, const bf16* __restrict__ W2b,
    const float* __restrict__ b2, float* __restrict__ feat2)
{
  __shared__ bf16 As[64 * LDA];
  __shared__ bf16 Bs[128 * LDA];
  int m0 = blockIdx.x << 6;
  int t = threadIdx.x;
  int wv = t >> 6, lane = t & 63;
  int lrow = lane & 15, q = lane >> 4;
  int n0 = wv * 32;
  f32x4 acc[4][2];
#pragma unroll
  for (int i = 0; i < 4; ++i)
#pragma unroll
    for (int j = 0; j < 2; ++j)
#pragma unroll
      for (int e = 0; e < 4; ++e) acc[i][j][e] = 0.f;

  for (int kp = 0; kp < 9; ++kp) {
    int kh = kp / 3, kw = kp - kh * 3;
    __syncthreads();
    // stage A: 64 px x 128 ci, fp32 -> bf16, stride-2 spatial gather
    for (int i = t; i < 2048; i += 256) {
      int row = i >> 5; int c4 = (i & 31) << 2;
      int m = m0 + row;
      int nimg = m / NPIX; int hw = m - nimg * NPIX;
      int oh = hw / 96, ow = hw - oh * 96;
      int ih = 2 * oh - 1 + kh, iw = 2 * ow - 1 + kw;
      float4 v = {0.f, 0.f, 0.f, 0.f};
      if ((unsigned)ih < 192u && (unsigned)iw < 192u)
        v = *(const float4*)&y2[(((size_t)nimg * 192 + ih) * 192 + iw) * 128 + c4];
      bf16x4 p;
      p[0] = (bf16)v.x; p[1] = (bf16)v.y; p[2] = (bf16)v.z; p[3] = (bf16)v.w;
      *(bf16x4*)&As[row * LDA + c4] = p;
    }
    // stage B: [co][ci] 128x128 bf16 with pad
    const bf16* Wk = W2b + kp * 16384;
    for (int i = t; i < 2048; i += 256) {
      int n = i >> 4; int k8 = (i & 15) << 3;
      *(bf16x8*)&Bs[n * LDA + k8] = *(const bf16x8*)&Wk[n * 128 + k8];
    }
    __syncthreads();
#pragma unroll
    for (int ks = 0; ks < 4; ++ks) {
      bf16x8 bfr0 = *(const bf16x8*)&Bs[(n0 + lrow) * LDA + ks * 32 + q * 8];
      bf16x8 bfr1 = *(const bf16x8*)&Bs[(n0 + 16 + lrow) * LDA + ks * 32 + q * 8];
#pragma unroll
      for (int mi = 0; mi < 4; ++mi) {
        bf16x8 afr = *(const bf16x8*)&As[(mi * 16 + lrow) * LDA + ks * 32 + q * 8];
        acc[mi][0] = __builtin_amdgcn_mfma_f32_16x16x32_bf16(afr, bfr0, acc[mi][0], 0, 0, 0);
        acc[mi][1] = __builtin_amdgcn_mfma_f32_16x16x32_bf16(afr, bfr1, acc[mi][1], 0, 0, 0);
      }
    }
  }
  // epilogue: D row = q*4+r, col = lrow (per 16x16 tile)
#pragma unroll
  for (int mi = 0; mi < 4; ++mi) {
#pragma unroll
    for (int nj = 0; nj < 2; ++nj) {
      int co = n0 + nj * 16 + lrow;
      float bb = b2[co];
#pragma unroll
      for (int r = 0; r < 4; ++r) {
        int m = m0 + mi * 16 + q * 4 + r;
        feat2[(size_t)m * 128 + co] = silu_f(acc[mi][nj][r] + bb);
      }
    }
  }
}

// ---------------------------------------------------------------------------
// Generic bf16-MFMA GEMM: C[M][Nc] = act(A_f32[M][128] @ W_b[Nc][128]^T + bias)
// Block 256 = 4 waves; tile 64 m x 128 n (blockIdx.y picks 128-col slab).
// store_mode 0: out[m*ostride+col]; 1: NCHW d_out + ReLU with channel offset.
// ---------------------------------------------------------------------------
__global__ __launch_bounds__(256) void mm_bf16_kernel(
    const float* __restrict__ A, const bf16* __restrict__ W,
    const float* __restrict__ bias, int Nc, int ostride, int act,
    int store_mode, int choff, float* __restrict__ out)
{
  __shared__ bf16 As[64 * LDA];
  __shared__ bf16 Bs[128 * LDA];
  int m0 = blockIdx.x << 6;
  int nb = blockIdx.y << 7;
  int cols_here = Nc - nb; if (cols_here > 128) cols_here = 128;
  int t = threadIdx.x;
  // stage A (contiguous 64x128 f32 -> bf16)
  for (int i = t; i < 2048; i += 256) {
    int row = i >> 5; int c4 = (i & 31) << 2;
    float4 v = *(const float4*)&A[(size_t)(m0 + row) * 128 + c4];
    bf16x4 p;
    p[0] = (bf16)v.x; p[1] = (bf16)v.y; p[2] = (bf16)v.z; p[3] = (bf16)v.w;
    *(bf16x4*)&As[row * LDA + c4] = p;
  }
  // stage B rows [nb, nb+128) ; zero rows beyond Nc slab
  bf16x8 zv;
#pragma unroll
  for (int e = 0; e < 8; ++e) zv[e] = (bf16)0.f;
  for (int i = t; i < 2048; i += 256) {
    int n = i >> 4; int k8 = (i & 15) << 3;
    bf16x8 v = (n < cols_here) ? *(const bf16x8*)&W[(size_t)(nb + n) * 128 + k8] : zv;
    *(bf16x8*)&Bs[n * LDA + k8] = v;
  }
  __syncthreads();

  int wv = t >> 6, lane = t & 63;
  int lrow = lane & 15, q = lane >> 4;
  int n0 = wv * 32;
  f32x4 acc[4][2];
#pragma unroll
  for (int i = 0; i < 4; ++i)
#pragma unroll
    for (int j = 0; j < 2; ++j)
#pragma unroll
      for (int e = 0; e < 4; ++e) acc[i][j][e] = 0.f;

#pragma unroll
  for (int ks = 0; ks < 4; ++ks) {
    bf16x8 bfr0 = *(const bf16x8*)&Bs[(n0 + lrow) * LDA + ks * 32 + q * 8];
    bf16x8 bfr1 = *(const bf16x8*)&Bs[(n0 + 16 + lrow) * LDA + ks * 32 + q * 8];
#pragma unroll
    for (int mi = 0; mi < 4; ++mi) {
      bf16x8 afr = *(const bf16x8*)&As[(mi * 16 + lrow) * LDA + ks * 32 + q * 8];
      acc[mi][0] = __builtin_amdgcn_mfma_f32_16x16x32_bf16(afr, bfr0, acc[mi][0], 0, 0, 0);
      acc[mi][1] = __builtin_amdgcn_mfma_f32_16x16x32_bf16(afr, bfr1, acc[mi][1], 0, 0, 0);
    }
  }

#pragma unroll
  for (int mi = 0; mi < 4; ++mi) {
#pragma unroll
    for (int nj = 0; nj < 2; ++nj) {
      int col = nb + n0 + nj * 16 + lrow;
      if (col >= Nc) continue;
      float bb = bias[col];
#pragma unroll
      for (int r = 0; r < 4; ++r) {
        int m = m0 + mi * 16 + q * 4 + r;
        float v = acc[mi][nj][r] + bb;
        if (act == 1) v = fmaxf(v, 0.f);
        if (store_mode == 0) {
          out[(size_t)m * ostride + col] = v;
        } else {
          int nn = m / NPIX; int hw = m - nn * NPIX;
          out[((size_t)(nn * 384 + choff + col)) * NPIX + hw] = v;
        }
      }
    }
  }
}

// ---------------------------------------------------------------------------
// Depthwise 3x3 + bias + LayerNorm + GELU(tanh)
// ---------------------------------------------------------------------------
__global__ __launch_bounds__(128) void dwln_kernel(
    const float* __restrict__ feat, const float* __restrict__ dw_w,
    const float* __restrict__ dw_b, const float* __restrict__ ln_g,
    const float* __restrict__ ln_b, float* __restrict__ dwg)
{
  int pixel = blockIdx.x;
  int n = pixel / NPIX; int hw = pixel - n * NPIX;
  int h = hw / 96; int w = hw - h * 96;
  int c = threadIdx.x;
  const float* fn = feat + (size_t)n * NPIX * 128 + c;
  float acc = dw_b[c];
#pragma unroll
  for (int kh = 0; kh < 3; ++kh) {
    int hh = h + kh - 1;
    if ((unsigned)hh >= 96u) continue;
#pragma unroll
    for (int kw = 0; kw < 3; ++kw) {
      int ww = w + kw - 1;
      if ((unsigned)ww >= 96u) continue;
      acc += fn[(hh * 96 + ww) * 128] * dw_w[(kh * 3 + kw) * 128 + c];
    }
  }
  __shared__ float rs[128], rq[128];
  rs[c] = acc; rq[c] = acc * acc;
  __syncthreads();
  for (int off = 64; off > 0; off >>= 1) {
    if (c < off) { rs[c] += rs[c + off]; rq[c] += rq[c + off]; }
    __syncthreads();
  }
  float mean = rs[0] * (1.f / 128.f);
  float var = rq[0] * (1.f / 128.f) - mean * mean;
  float xn = (acc - mean) * rsqrtf(var + EPSV) * ln_g[c] + ln_b[c];
  float z = 0.7978845608028654f * (xn + 0.044715f * xn * xn * xn);
  float th;
  if (z > 15.f) th = 1.f;
  else if (z < -15.f) th = -1.f;
  else { float e = __expf(2.f * z); th = (e - 1.f) / (e + 1.f); }
  dwg[(size_t)pixel * 128 + c] = 0.5f * xn * (1.f + th);
}

// ---------------------------------------------------------------------------
// Deformable sampling; offm rows are stride-224 now (pad cols 216..223)
// block 256 = 2 px x 8 g x 16 c
// ---------------------------------------------------------------------------
__global__ __launch_bounds__(256) void sample_kernel(
    const float* __restrict__ xp, const float* __restrict__ offm,
    float* __restrict__ vagg)
{
  __shared__ float S[448];
  int t = threadIdx.x;
  int bid = blockIdx.x;
  for (int i = t; i < 448; i += 256) S[i] = offm[(size_t)bid * 448 + i];
  __syncthreads();
  int pxl = t >> 7;
  int g = (t >> 4) & 7;
  int c = t & 15;
  int pixel = bid * 2 + pxl;
  int n = pixel / NPIX; int hw = pixel - n * NPIX;
  int h = hw / 96; int w = hw - h * 96;
  const float* Sp = S + pxl * 224;
  float lg[9]; float mx = -1e30f;
#pragma unroll
  for (int p = 0; p < 9; ++p) { lg[p] = Sp[144 + g * 9 + p]; mx = fmaxf(mx, lg[p]); }
  float se = 0.f;
#pragma unroll
  for (int p = 0; p < 9; ++p) { lg[p] = __expf(lg[p] - mx); se += lg[p]; }
  float inv = 1.f / se;
  const float* xpn = xp + (size_t)n * NPIX * 128 + g * 16 + c;
  float acc = 0.f;
#pragma unroll
  for (int p = 0; p < 9; ++p) {
    float dx = Sp[g * 18 + p * 2], dy = Sp[g * 18 + p * 2 + 1];
    float pyu = (float)(h + p / 3 - 1) + dy;
    float pxu = (float)(w + p % 3 - 1) + dx;
    float yf = floorf(pyu), xf = floorf(pxu);
    float wy = pyu - yf, wx = pxu - xf;
    int y0 = (int)yf, x0 = (int)xf;
    float w00 = (1.f - wy) * (1.f - wx), w01 = (1.f - wy) * wx;
    float w10 = wy * (1.f - wx), w11 = wy * wx;
    float v = 0.f;
    if ((unsigned)y0 < 96u) {
      if ((unsigned)x0 < 96u)       v += w00 * xpn[(y0 * 96 + x0) * 128];
      if ((unsigned)(x0 + 1) < 96u) v += w01 * xpn[(y0 * 96 + x0 + 1) * 128];
    }
    if ((unsigned)(y0 + 1) < 96u) {
      if ((unsigned)x0 < 96u)       v += w10 * xpn[((y0 + 1) * 96 + x0) * 128];
      if ((unsigned)(x0 + 1) < 96u) v += w11 * xpn[((y0 + 1) * 96 + x0 + 1) * 128];
    }
    acc += lg[p] * inv * v;
  }
  vagg[(size_t)pixel * 128 + g * 16 + c] = acc;
}

// ---------------------------------------------------------------------------
__global__ __launch_bounds__(256) void copy_x0_kernel(
    const float4* __restrict__ x0, float4* __restrict__ out)
{
  int idx = blockIdx.x * 256 + threadIdx.x;
  int n = idx / (128 * 2304);
  int r = idx - n * (128 * 2304);
  out[(size_t)(n * 384 + 128) * 2304 + r] = x0[(size_t)n * 128 * 2304 + r];
}

// ---------------------------------------------------------------------------
extern "C" void kernel_launch(void* const* d_in, const int* in_sizes, int n_in,
                              void* d_out, int out_size, void* d_ws, size_t ws_size,
                              hipStream_t stream)
{
  (void)in_sizes; (void)n_in; (void)out_size; (void)ws_size;
  const float* x0      = (const float*)d_in[0];
  const float* x1      = (const float*)d_in[1];
  const float* x2      = (const float*)d_in[2];
  const float* conv_w  = (const float*)d_in[3];
  const float* conv_g  = (const float*)d_in[4];
  const float* conv_b  = (const float*)d_in[5];
  const float* conv_rm = (const float*)d_in[6];
  const float* conv_rv = (const float*)d_in[7];
  const float* conv1_w = (const float*)d_in[8];
  const float* conv1_g = (const float*)d_in[9];
  const float* conv1_b = (const float*)d_in[10];
  const float* conv1_rm= (const float*)d_in[11];
  const float* conv1_rv= (const float*)d_in[12];
  const float* conv2_w = (const float*)d_in[13];
  const float* conv2_g = (const float*)d_in[14];
  const float* conv2_b = (const float*)d_in[15];
  const float* conv2_rm= (const float*)d_in[16];
  const float* conv2_rv= (const float*)d_in[17];
  const float* dw_w    = (const float*)d_in[18];
  const float* dw_b    = (const float*)d_in[19];
  const float* ln_g    = (const float*)d_in[20];
  const float* ln_b    = (const float*)d_in[21];
  const float* off_w   = (const float*)d_in[22];
  const float* off_b   = (const float*)d_in[23];
  const float* m_w     = (const float*)d_in[24];
  const float* m_b     = (const float*)d_in[25];
  const float* ip_w    = (const float*)d_in[26];
  const float* ip_b    = (const float*)d_in[27];
  const float* op_w    = (const float*)d_in[28];
  const float* op_b    = (const float*)d_in[29];
  float* out = (float*)d_out;
  float* ws = (float*)d_ws;

  // workspace layout (floats)
  float* feat1 = ws;                       // 4,718,592
  float* feat2 = ws + 4718592;             // 4,718,592 (y1 aliases start, dead before conv2)
  float* y1    = feat2;
  float* R     = ws + 9437184;             // scratch region (22,118,400 capacity)
  float* y2    = R;                        // 18,874,368 — dead after conv2
  float* xp    = R;                        // 4,718,592
  float* dwg   = R + 4718592;              // 4,718,592 — dead after offm gemm
  float* vagg  = dwg;                      // aliases dwg (live: sample -> op gemm)
  float* offm  = R + 9437184;              // 8,257,536 (stride 224)
  float* WTSf  = ws + 31555584;            // 41,568 floats
  bf16*  WTSb  = (bf16*)(WTSf + 41568);    // 208,896 bf16

  float* W1r  = WTSf;
  float* b1   = WTSf + 32768;
  float* W1br = WTSf + 32896;
  float* b1b  = WTSf + 41088;
  float* b2   = WTSf + 41216;
  float* bom  = WTSf + 41344;
  bf16*  W2b  = WTSb;
  bf16*  Wipb = WTSb + 147456;
  bf16*  Womb = WTSb + 163840;
  bf16*  Wopb = WTSb + 192512;

  prep_kernel<<<979, 256, 0, stream>>>(
      conv_w, conv_g, conv_b, conv_rm, conv_rv,
      conv1_w, conv1_g, conv1_b, conv1_rm, conv1_rv,
      conv2_w, conv2_g, conv2_b, conv2_rm, conv2_rv,
      ip_w, op_w, off_w, m_w, off_b, m_b, WTSf, WTSb);

  conv1x1_kernel<<<288, 256, 0, stream>>>(x1, W1r, b1, 256, 2304, y1);
  upsample_kernel<<<18432, 256, 0, stream>>>(y1, feat1);

  conv1x1_kernel<<<4608, 256, 0, stream>>>(x2, W1br, b1b, 64, 36864, y2);
  conv2_mfma_kernel<<<576, 256, 0, stream>>>(y2, W2b, b2, feat2);

  for (int d = 0; d < 2; ++d) {
    const float* feat = d ? feat2 : feat1;
    int choff = d ? 256 : 0;
    mm_bf16_kernel<<<dim3(576, 1), 256, 0, stream>>>(feat, Wipb, ip_b, 128, 128, 0, 0, 0, xp);
    dwln_kernel<<<36864, 128, 0, stream>>>(feat, dw_w, dw_b, ln_g, ln_b, dwg);
    mm_bf16_kernel<<<dim3(576, 2), 256, 0, stream>>>(dwg, Womb, bom, 224, 224, 0, 0, 0, offm);
    sample_kernel<<<18432, 256, 0, stream>>>(xp, offm, vagg);
    mm_bf16_kernel<<<dim3(576, 1), 256, 0, stream>>>(vagg, Wopb, op_b, 128, 0, 1, 1, choff, out);
  }

  copy_x0_kernel<<<4608, 256, 0, stream>>>((const float4*)x0, (float4*)out);
}

// Round 3
// 478.007 us; speedup vs baseline: 2.3666x; 1.4451x over previous
//
#include <hip/hip_runtime.h>
#include <cstdint>
#include <cstddef>

#define EPSV 1e-5f
#define NPIX 9216          // 96*96
#define MTOT 36864         // 4*96*96
#define LDA 136            // padded bf16 k-stride (128 + 8)

typedef __bf16 bf16;
typedef __attribute__((ext_vector_type(8))) __bf16 bf16x8;
typedef __attribute__((ext_vector_type(4))) __bf16 bf16x4;
typedef __attribute__((ext_vector_type(4))) float  f32x4;

__device__ __forceinline__ float silu_f(float v) { return v / (1.f + __expf(-v)); }

// ---------------------------------------------------------------------------
// WTSf (float) layout:
//   0      W1r  [256][128]   (conv_w * s, [ci][co])
//   32768  b1   [128]
//   32896  (unused, legacy)  8192
//   41088  b1b  [128]
//   41216  b2   [128]
//   41344  bom  [224]  (off 144 | m 72 | pad 8 zeros)
//   total 41568 floats
// WTSb (bf16) layout — all [co][ci] for MFMA B-operand:
//   0       W2b  [9][128][128]  (BN-folded)
//   147456  Wipb [128][128]
//   163840  Womb [224][128]  (rows 216..223 zero)
//   192512  Wopb [128][128]
//   208896  W1bb [128][64]   (BN-folded conv1)
//   total 217088 bf16
// ---------------------------------------------------------------------------
__global__ __launch_bounds__(256) void prep_kernel(
    const float* __restrict__ conv_w, const float* __restrict__ conv_g,
    const float* __restrict__ conv_b, const float* __restrict__ conv_rm, const float* __restrict__ conv_rv,
    const float* __restrict__ conv1_w, const float* __restrict__ conv1_g,
    const float* __restrict__ conv1_b, const float* __restrict__ conv1_rm, const float* __restrict__ conv1_rv,
    const float* __restrict__ conv2_w, const float* __restrict__ conv2_g,
    const float* __restrict__ conv2_bb, const float* __restrict__ conv2_rm, const float* __restrict__ conv2_rv,
    const float* __restrict__ ip_w, const float* __restrict__ op_w,
    const float* __restrict__ off_w, const float* __restrict__ m_w,
    const float* __restrict__ off_b, const float* __restrict__ m_b,
    float* __restrict__ WTSf, bf16* __restrict__ WTSb)
{
  int idx = blockIdx.x * 256 + threadIdx.x;
  if (idx < 41568) {
    if (idx < 32768) {
      int ci = idx >> 7, co = idx & 127;
      float s = conv_g[co] * rsqrtf(conv_rv[co] + EPSV);
      WTSf[idx] = conv_w[co * 256 + ci] * s;
    } else if (idx < 32896) {
      int co = idx - 32768;
      float s = conv_g[co] * rsqrtf(conv_rv[co] + EPSV);
      WTSf[idx] = conv_b[co] - conv_rm[co] * s;
    } else if (idx < 41088) {
      WTSf[idx] = 0.f;   // legacy slot
    } else if (idx < 41216) {
      int co = idx - 41088;
      float s = conv1_g[co] * rsqrtf(conv1_rv[co] + EPSV);
      WTSf[idx] = conv1_b[co] - conv1_rm[co] * s;
    } else if (idx < 41344) {
      int co = idx - 41216;
      float s = conv2_g[co] * rsqrtf(conv2_rv[co] + EPSV);
      WTSf[idx] = conv2_bb[co] - conv2_rm[co] * s;
    } else {
      int col = idx - 41344;
      WTSf[idx] = (col < 144) ? off_b[col] : (col < 216 ? m_b[col - 144] : 0.f);
    }
  } else {
    int j = idx - 41568;
    if (j < 147456) {
      int kp = j >> 14; int r = j & 16383; int co = r >> 7, ci = r & 127;
      float s = conv2_g[co] * rsqrtf(conv2_rv[co] + EPSV);
      WTSb[j] = (bf16)(conv2_w[(co * 128 + ci) * 9 + kp] * s);
    } else if (j < 163840) {
      int r = j - 147456; int co = r >> 7, ci = r & 127;
      WTSb[j] = (bf16)ip_w[co * 128 + ci];
    } else if (j < 192512) {
      int r = j - 163840; int co = r >> 7, ci = r & 127;
      float v = (co < 144) ? off_w[co * 128 + ci] : (co < 216 ? m_w[(co - 144) * 128 + ci] : 0.f);
      WTSb[j] = (bf16)v;
    } else if (j < 208896) {
      int r = j - 192512; int co = r >> 7, ci = r & 127;
      WTSb[j] = (bf16)op_w[co * 128 + ci];
    } else if (j < 217088) {
      int r = j - 208896; int co = r >> 6, ci = r & 63;
      float s = conv1_g[co] * rsqrtf(conv1_rv[co] + EPSV);
      WTSb[j] = (bf16)(conv1_w[co * 64 + ci] * s);
    }
  }
}

// ---------------------------------------------------------------------------
// conv1x1 + folded BN + SiLU (fp32 vector) — used only for the small x1 path
// ---------------------------------------------------------------------------
__global__ __launch_bounds__(256) void conv1x1_kernel(
    const float* __restrict__ x, const float* __restrict__ Wm,
    const float* __restrict__ bias, int K, int HW, float* __restrict__ out)
{
  __shared__ float As[64 * 32];    // [ci][px]
  __shared__ float Bs[64 * 128];   // [ci][co]
  int tilesPerImg = HW >> 5;
  int n = blockIdx.x / tilesPerImg;
  int hw0 = (blockIdx.x % tilesPerImg) << 5;
  const float* xn = x + (size_t)n * K * HW;
  int t = threadIdx.x;
  int co4 = (t & 31) << 2;
  int px4 = (t >> 5) << 2;
  float acc[4][4];
#pragma unroll
  for (int i = 0; i < 4; ++i)
#pragma unroll
    for (int j = 0; j < 4; ++j) acc[i][j] = 0.f;

  for (int k0 = 0; k0 < K; k0 += 64) {
    if (k0) __syncthreads();
    for (int i = t; i < 64 * 32; i += 256) {
      int ci = i >> 5, px = i & 31;
      As[i] = xn[(size_t)(k0 + ci) * HW + hw0 + px];
    }
    for (int i = t; i < 64 * 128; i += 256) {
      int ci = i >> 7, co = i & 127;
      Bs[i] = Wm[(size_t)(k0 + ci) * 128 + co];
    }
    __syncthreads();
#pragma unroll 4
    for (int c = 0; c < 64; ++c) {
      float4 a = *(const float4*)&As[c * 32 + px4];
      float4 b = *(const float4*)&Bs[c * 128 + co4];
      acc[0][0] += a.x * b.x; acc[0][1] += a.x * b.y; acc[0][2] += a.x * b.z; acc[0][3] += a.x * b.w;
      acc[1][0] += a.y * b.x; acc[1][1] += a.y * b.y; acc[1][2] += a.y * b.z; acc[1][3] += a.y * b.w;
      acc[2][0] += a.z * b.x; acc[2][1] += a.z * b.y; acc[2][2] += a.z * b.z; acc[2][3] += a.z * b.w;
      acc[3][0] += a.w * b.x; acc[3][1] += a.w * b.y; acc[3][2] += a.w * b.z; acc[3][3] += a.w * b.w;
    }
  }
  float4 bb = *(const float4*)&bias[co4];
#pragma unroll
  for (int i = 0; i < 4; ++i) {
    float4 v;
    v.x = silu_f(acc[i][0] + bb.x);
    v.y = silu_f(acc[i][1] + bb.y);
    v.z = silu_f(acc[i][2] + bb.z);
    v.w = silu_f(acc[i][3] + bb.w);
    *(float4*)&out[((size_t)(n * HW) + hw0 + px4 + i) * 128 + co4] = v;
  }
}

// ---------------------------------------------------------------------------
// x2 1x1 conv via MFMA: NCHW fp32 (64ch) -> y2b NHWC bf16 (128ch) + BN + SiLU
// block 256 = 4 waves; tile 64 px x 128 co; K=64 (2 mfma k-steps)
// ---------------------------------------------------------------------------
__global__ __launch_bounds__(256) void c1x2_mfma_kernel(
    const float* __restrict__ x2, const bf16* __restrict__ W1bb,
    const float* __restrict__ b1b, bf16* __restrict__ y2b)
{
  __shared__ bf16 As[64 * LDA];   // [px][ci<64]
  __shared__ bf16 Bs[128 * LDA];  // [co][ci<64]
  int m0 = blockIdx.x << 6;
  int t = threadIdx.x;
  int n = m0 / 36864; int hw0 = m0 - n * 36864;
  const float* xn = x2 + (size_t)n * 64 * 36864;
  // A: for fixed ci4-group, 64 lanes read 64 consecutive px (coalesced), 4 ci each
  for (int i = t; i < 1024; i += 256) {
    int px = i & 63; int ci4 = (i >> 6) << 2;
    bf16x4 p;
#pragma unroll
    for (int j = 0; j < 4; ++j)
      p[j] = (bf16)xn[(size_t)(ci4 + j) * 36864 + hw0 + px];
    *(bf16x4*)&As[px * LDA + ci4] = p;
  }
  for (int i = t; i < 1024; i += 256) {
    int co = i >> 3; int k8 = (i & 7) << 3;
    *(bf16x8*)&Bs[co * LDA + k8] = *(const bf16x8*)&W1bb[co * 64 + k8];
  }
  __syncthreads();

  int wv = t >> 6, lane = t & 63;
  int lrow = lane & 15, q = lane >> 4;
  int n0 = wv * 32;
  f32x4 acc[4][2];
#pragma unroll
  for (int i = 0; i < 4; ++i)
#pragma unroll
    for (int j = 0; j < 2; ++j)
#pragma unroll
      for (int e = 0; e < 4; ++e) acc[i][j][e] = 0.f;

#pragma unroll
  for (int ks = 0; ks < 2; ++ks) {
    int ko = ks * 32 + q * 8;
    bf16x8 bfr0 = *(const bf16x8*)&Bs[(n0 + lrow) * LDA + ko];
    bf16x8 bfr1 = *(const bf16x8*)&Bs[(n0 + 16 + lrow) * LDA + ko];
#pragma unroll
    for (int mi = 0; mi < 4; ++mi) {
      bf16x8 afr = *(const bf16x8*)&As[(mi * 16 + lrow) * LDA + ko];
      acc[mi][0] = __builtin_amdgcn_mfma_f32_16x16x32_bf16(afr, bfr0, acc[mi][0], 0, 0, 0);
      acc[mi][1] = __builtin_amdgcn_mfma_f32_16x16x32_bf16(afr, bfr1, acc[mi][1], 0, 0, 0);
    }
  }
#pragma unroll
  for (int mi = 0; mi < 4; ++mi) {
#pragma unroll
    for (int nj = 0; nj < 2; ++nj) {
      int co = n0 + nj * 16 + lrow;
      float bb = b1b[co];
#pragma unroll
      for (int r = 0; r < 4; ++r) {
        int m = m0 + mi * 16 + q * 4 + r;
        y2b[(size_t)m * 128 + co] = (bf16)silu_f(acc[mi][nj][r] + bb);
      }
    }
  }
}

// ---------------------------------------------------------------------------
// bilinear 2x upsample, NHWC fp32
// ---------------------------------------------------------------------------
__global__ __launch_bounds__(256) void upsample_kernel(
    const float* __restrict__ y1, float* __restrict__ feat1)
{
  int idx = blockIdx.x * 256 + threadIdx.x;
  int c = idx & 127;
  int pw = idx >> 7;
  int ow = pw % 96; int t1 = pw / 96;
  int oh = t1 % 96; int n = t1 / 96;
  float sh = oh * 0.5f - 0.25f, sw = ow * 0.5f - 0.25f;
  float hf = floorf(sh), wf = floorf(sw);
  float fy = sh - hf, fx = sw - wf;
  int h0 = (int)hf, w0 = (int)wf;
  int h0c = max(h0, 0), h1c = min(h0 + 1, 47);
  int w0c = max(w0, 0), w1c = min(w0 + 1, 47);
  const float* yn = y1 + (size_t)n * 48 * 48 * 128 + c;
  float v00 = yn[(h0c * 48 + w0c) * 128];
  float v01 = yn[(h0c * 48 + w1c) * 128];
  float v10 = yn[(h1c * 48 + w0c) * 128];
  float v11 = yn[(h1c * 48 + w1c) * 128];
  feat1[idx] = (1.f - fy) * ((1.f - fx) * v00 + fx * v01) + fy * ((1.f - fx) * v10 + fx * v11);
}

// ---------------------------------------------------------------------------
// conv2 via MFMA: 3x3 s2 p1 + BN + SiLU. y2b NHWC bf16 -> feat2 NHWC fp32.
// ---------------------------------------------------------------------------
__global__ __launch_bounds__(256) void conv2_mfma_kernel(
    const bf16* __restrict__ y2b, const bf16* __restrict__ W2b,
    const float* __restrict__ b2, float* __restrict__ feat2)
{
  __shared__ bf16 As[64 * LDA];
  __shared__ bf16 Bs[128 * LDA];
  int m0 = blockIdx.x << 6;
  int t = threadIdx.x;
  int wv = t >> 6, lane = t & 63;
  int lrow = lane & 15, q = lane >> 4;
  int n0 = wv * 32;
  f32x4 acc[4][2];
#pragma unroll
  for (int i = 0; i < 4; ++i)
#pragma unroll
    for (int j = 0; j < 2; ++j)
#pragma unroll
      for (int e = 0; e < 4; ++e) acc[i][j][e] = 0.f;
  bf16x8 zv;
#pragma unroll
  for (int e = 0; e < 8; ++e) zv[e] = (bf16)0.f;

  for (int kp = 0; kp < 9; ++kp) {
    int kh = kp / 3, kw = kp - kh * 3;
    __syncthreads();
    // stage A: 64 px x 128 ci bf16 direct copies (16B)
    for (int i = t; i < 1024; i += 256) {
      int row = i >> 4; int c8 = (i & 15) << 3;
      int m = m0 + row;
      int nimg = m / NPIX; int hw = m - nimg * NPIX;
      int oh = hw / 96, ow = hw - oh * 96;
      int ih = 2 * oh - 1 + kh, iw = 2 * ow - 1 + kw;
      bf16x8 v = zv;
      if ((unsigned)ih < 192u && (unsigned)iw < 192u)
        v = *(const bf16x8*)&y2b[(((size_t)nimg * 192 + ih) * 192 + iw) * 128 + c8];
      *(bf16x8*)&As[row * LDA + c8] = v;
    }
    const bf16* Wk = W2b + kp * 16384;
    for (int i = t; i < 2048; i += 256) {
      int nn = i >> 4; int k8 = (i & 15) << 3;
      *(bf16x8*)&Bs[nn * LDA + k8] = *(const bf16x8*)&Wk[nn * 128 + k8];
    }
    __syncthreads();
#pragma unroll
    for (int ks = 0; ks < 4; ++ks) {
      bf16x8 bfr0 = *(const bf16x8*)&Bs[(n0 + lrow) * LDA + ks * 32 + q * 8];
      bf16x8 bfr1 = *(const bf16x8*)&Bs[(n0 + 16 + lrow) * LDA + ks * 32 + q * 8];
#pragma unroll
      for (int mi = 0; mi < 4; ++mi) {
        bf16x8 afr = *(const bf16x8*)&As[(mi * 16 + lrow) * LDA + ks * 32 + q * 8];
        acc[mi][0] = __builtin_amdgcn_mfma_f32_16x16x32_bf16(afr, bfr0, acc[mi][0], 0, 0, 0);
        acc[mi][1] = __builtin_amdgcn_mfma_f32_16x16x32_bf16(afr, bfr1, acc[mi][1], 0, 0, 0);
      }
    }
  }
#pragma unroll
  for (int mi = 0; mi < 4; ++mi) {
#pragma unroll
    for (int nj = 0; nj < 2; ++nj) {
      int co = n0 + nj * 16 + lrow;
      float bb = b2[co];
#pragma unroll
      for (int r = 0; r < 4; ++r) {
        int m = m0 + mi * 16 + q * 4 + r;
        feat2[(size_t)m * 128 + co] = silu_f(acc[mi][nj][r] + bb);
      }
    }
  }
}

// ---------------------------------------------------------------------------
// Generic bf16-MFMA GEMM (A fp32 [M][128], W bf16 [Nc][128])
// ---------------------------------------------------------------------------
__global__ __launch_bounds__(256) void mm_bf16_kernel(
    const float* __restrict__ A, const bf16* __restrict__ W,
    const float* __restrict__ bias, int Nc, int ostride, int act,
    int store_mode, int choff, float* __restrict__ out)
{
  __shared__ bf16 As[64 * LDA];
  __shared__ bf16 Bs[128 * LDA];
  int m0 = blockIdx.x << 6;
  int nb = blockIdx.y << 7;
  int cols_here = Nc - nb; if (cols_here > 128) cols_here = 128;
  int t = threadIdx.x;
  for (int i = t; i < 2048; i += 256) {
    int row = i >> 5; int c4 = (i & 31) << 2;
    float4 v = *(const float4*)&A[(size_t)(m0 + row) * 128 + c4];
    bf16x4 p;
    p[0] = (bf16)v.x; p[1] = (bf16)v.y; p[2] = (bf16)v.z; p[3] = (bf16)v.w;
    *(bf16x4*)&As[row * LDA + c4] = p;
  }
  bf16x8 zv;
#pragma unroll
  for (int e = 0; e < 8; ++e) zv[e] = (bf16)0.f;
  for (int i = t; i < 2048; i += 256) {
    int n = i >> 4; int k8 = (i & 15) << 3;
    bf16x8 v = (n < cols_here) ? *(const bf16x8*)&W[(size_t)(nb + n) * 128 + k8] : zv;
    *(bf16x8*)&Bs[n * LDA + k8] = v;
  }
  __syncthreads();

  int wv = t >> 6, lane = t & 63;
  int lrow = lane & 15, q = lane >> 4;
  int n0 = wv * 32;
  f32x4 acc[4][2];
#pragma unroll
  for (int i = 0; i < 4; ++i)
#pragma unroll
    for (int j = 0; j < 2; ++j)
#pragma unroll
      for (int e = 0; e < 4; ++e) acc[i][j][e] = 0.f;

#pragma unroll
  for (int ks = 0; ks < 4; ++ks) {
    bf16x8 bfr0 = *(const bf16x8*)&Bs[(n0 + lrow) * LDA + ks * 32 + q * 8];
    bf16x8 bfr1 = *(const bf16x8*)&Bs[(n0 + 16 + lrow) * LDA + ks * 32 + q * 8];
#pragma unroll
    for (int mi = 0; mi < 4; ++mi) {
      bf16x8 afr = *(const bf16x8*)&As[(mi * 16 + lrow) * LDA + ks * 32 + q * 8];
      acc[mi][0] = __builtin_amdgcn_mfma_f32_16x16x32_bf16(afr, bfr0, acc[mi][0], 0, 0, 0);
      acc[mi][1] = __builtin_amdgcn_mfma_f32_16x16x32_bf16(afr, bfr1, acc[mi][1], 0, 0, 0);
    }
  }

#pragma unroll
  for (int mi = 0; mi < 4; ++mi) {
#pragma unroll
    for (int nj = 0; nj < 2; ++nj) {
      int col = nb + n0 + nj * 16 + lrow;
      if (col >= Nc) continue;
      float bb = bias[col];
#pragma unroll
      for (int r = 0; r < 4; ++r) {
        int m = m0 + mi * 16 + q * 4 + r;
        float v = acc[mi][nj][r] + bb;
        if (act == 1) v = fmaxf(v, 0.f);
        if (store_mode == 0) {
          out[(size_t)m * ostride + col] = v;
        } else {
          int nn = m / NPIX; int hw = m - nn * NPIX;
          out[((size_t)(nn * 384 + choff + col)) * NPIX + hw] = v;
        }
      }
    }
  }
}

// ---------------------------------------------------------------------------
// Depthwise 3x3 + bias + LayerNorm + GELU(tanh), float4 lanes
// block 256 = 8 px x 32 thr; thread handles 4 channels
// ---------------------------------------------------------------------------
__global__ __launch_bounds__(256) void dwln_kernel(
    const float* __restrict__ feat, const float* __restrict__ dw_w,
    const float* __restrict__ dw_b, const float* __restrict__ ln_g,
    const float* __restrict__ ln_b, float* __restrict__ dwg)
{
  int t = threadIdx.x;
  int pxl = t >> 5;
  int c4 = (t & 31) << 2;
  int pixel = blockIdx.x * 8 + pxl;
  int n = pixel / NPIX; int hw = pixel - n * NPIX;
  int h = hw / 96; int w = hw - h * 96;
  const float* fn = feat + (size_t)n * NPIX * 128 + c4;
  float4 acc = *(const float4*)&dw_b[c4];
#pragma unroll
  for (int kh = 0; kh < 3; ++kh) {
    int hh = h + kh - 1;
    if ((unsigned)hh >= 96u) continue;
#pragma unroll
    for (int kw = 0; kw < 3; ++kw) {
      int ww = w + kw - 1;
      if ((unsigned)ww >= 96u) continue;
      float4 v = *(const float4*)&fn[(hh * 96 + ww) * 128];
      float4 wt = *(const float4*)&dw_w[(kh * 3 + kw) * 128 + c4];
      acc.x += v.x * wt.x; acc.y += v.y * wt.y; acc.z += v.z * wt.z; acc.w += v.w * wt.w;
    }
  }
  float s = acc.x + acc.y + acc.z + acc.w;
  float qs = acc.x * acc.x + acc.y * acc.y + acc.z * acc.z + acc.w * acc.w;
#pragma unroll
  for (int off = 16; off > 0; off >>= 1) {
    s  += __shfl_xor(s, off);
    qs += __shfl_xor(qs, off);
  }
  float mean = s * (1.f / 128.f);
  float var = qs * (1.f / 128.f) - mean * mean;
  float rstd = rsqrtf(var + EPSV);
  float4 g = *(const float4*)&ln_g[c4];
  float4 b = *(const float4*)&ln_b[c4];
  float4 o;
  float* ap = (float*)&acc; float* gp = (float*)&g; float* bp = (float*)&b; float* op = (float*)&o;
#pragma unroll
  for (int e = 0; e < 4; ++e) {
    float xn = (ap[e] - mean) * rstd * gp[e] + bp[e];
    float z = 0.7978845608028654f * (xn + 0.044715f * xn * xn * xn);
    float th;
    if (z > 15.f) th = 1.f;
    else if (z < -15.f) th = -1.f;
    else { float e2 = __expf(2.f * z); th = (e2 - 1.f) / (e2 + 1.f); }
    op[e] = 0.5f * xn * (1.f + th);
  }
  *(float4*)&dwg[(size_t)pixel * 128 + c4] = o;
}

// ---------------------------------------------------------------------------
// Deformable sampling, float4 lanes: block 256 = 8 px x 8 g x 4 c4
// ---------------------------------------------------------------------------
__global__ __launch_bounds__(256) void sample_kernel(
    const float* __restrict__ xp, const float* __restrict__ offm,
    float* __restrict__ vagg)
{
  __shared__ float S[8 * 224];
  int t = threadIdx.x;
  int bid = blockIdx.x;
  for (int i = t; i < 1792; i += 256) S[i] = offm[(size_t)bid * 1792 + i];
  __syncthreads();
  int pxl = t >> 5;
  int g = (t >> 2) & 7;
  int c4 = (t & 3) << 2;
  int pixel = bid * 8 + pxl;
  int n = pixel / NPIX; int hw = pixel - n * NPIX;
  int h = hw / 96; int w = hw - h * 96;
  const float* Sp = S + pxl * 224;
  float lg[9]; float mx = -1e30f;
#pragma unroll
  for (int p = 0; p < 9; ++p) { lg[p] = Sp[144 + g * 9 + p]; mx = fmaxf(mx, lg[p]); }
  float se = 0.f;
#pragma unroll
  for (int p = 0; p < 9; ++p) { lg[p] = __expf(lg[p] - mx); se += lg[p]; }
  float inv = 1.f / se;
  const float* xpn = xp + (size_t)n * NPIX * 128 + g * 16 + c4;
  float4 acc = {0.f, 0.f, 0.f, 0.f};
#pragma unroll
  for (int p = 0; p < 9; ++p) {
    float dx = Sp[g * 18 + p * 2], dy = Sp[g * 18 + p * 2 + 1];
    float pyu = (float)(h + p / 3 - 1) + dy;
    float pxu = (float)(w + p % 3 - 1) + dx;
    float yf = floorf(pyu), xf = floorf(pxu);
    float wy = pyu - yf, wx = pxu - xf;
    int y0 = (int)yf, x0 = (int)xf;
    // validity folded into 1-D weights; coords clamped so loads are always safe
    float ay0 = ((unsigned)y0 < 96u) ? (1.f - wy) : 0.f;
    float ay1 = ((unsigned)(y0 + 1) < 96u) ? wy : 0.f;
    float ax0 = ((unsigned)x0 < 96u) ? (1.f - wx) : 0.f;
    float ax1 = ((unsigned)(x0 + 1) < 96u) ? wx : 0.f;
    int y0c = min(max(y0, 0), 95), y1c = min(max(y0 + 1, 0), 95);
    int x0c = min(max(x0, 0), 95), x1c = min(max(x0 + 1, 0), 95);
    float w00 = ay0 * ax0, w01 = ay0 * ax1, w10 = ay1 * ax0, w11 = ay1 * ax1;
    float4 v00 = *(const float4*)&xpn[(y0c * 96 + x0c) * 128];
    float4 v01 = *(const float4*)&xpn[(y0c * 96 + x1c) * 128];
    float4 v10 = *(const float4*)&xpn[(y1c * 96 + x0c) * 128];
    float4 v11 = *(const float4*)&xpn[(y1c * 96 + x1c) * 128];
    float mp = lg[p] * inv;
    acc.x += mp * (w00 * v00.x + w01 * v01.x + w10 * v10.x + w11 * v11.x);
    acc.y += mp * (w00 * v00.y + w01 * v01.y + w10 * v10.y + w11 * v11.y);
    acc.z += mp * (w00 * v00.z + w01 * v01.z + w10 * v10.z + w11 * v11.z);
    acc.w += mp * (w00 * v00.w + w01 * v01.w + w10 * v10.w + w11 * v11.w);
  }
  *(float4*)&vagg[(size_t)pixel * 128 + g * 16 + c4] = acc;
}

// ---------------------------------------------------------------------------
__global__ __launch_bounds__(256) void copy_x0_kernel(
    const float4* __restrict__ x0, float4* __restrict__ out)
{
  int idx = blockIdx.x * 256 + threadIdx.x;
  int n = idx / (128 * 2304);
  int r = idx - n * (128 * 2304);
  out[(size_t)(n * 384 + 128) * 2304 + r] = x0[(size_t)n * 128 * 2304 + r];
}

// ---------------------------------------------------------------------------
extern "C" void kernel_launch(void* const* d_in, const int* in_sizes, int n_in,
                              void* d_out, int out_size, void* d_ws, size_t ws_size,
                              hipStream_t stream)
{
  (void)in_sizes; (void)n_in; (void)out_size; (void)ws_size;
  const float* x0      = (const float*)d_in[0];
  const float* x1      = (const float*)d_in[1];
  const float* x2      = (const float*)d_in[2];
  const float* conv_w  = (const float*)d_in[3];
  const float* conv_g  = (const float*)d_in[4];
  const float* conv_b  = (const float*)d_in[5];
  const float* conv_rm = (const float*)d_in[6];
  const float* conv_rv = (const float*)d_in[7];
  const float* conv1_w = (const float*)d_in[8];
  const float* conv1_g = (const float*)d_in[9];
  const float* conv1_b = (const float*)d_in[10];
  const float* conv1_rm= (const float*)d_in[11];
  const float* conv1_rv= (const float*)d_in[12];
  const float* conv2_w = (const float*)d_in[13];
  const float* conv2_g = (const float*)d_in[14];
  const float* conv2_b = (const float*)d_in[15];
  const float* conv2_rm= (const float*)d_in[16];
  const float* conv2_rv= (const float*)d_in[17];
  const float* dw_w    = (const float*)d_in[18];
  const float* dw_b    = (const float*)d_in[19];
  const float* ln_g    = (const float*)d_in[20];
  const float* ln_b    = (const float*)d_in[21];
  const float* off_w   = (const float*)d_in[22];
  const float* off_b   = (const float*)d_in[23];
  const float* m_w     = (const float*)d_in[24];
  const float* m_b     = (const float*)d_in[25];
  const float* ip_w    = (const float*)d_in[26];
  const float* ip_b    = (const float*)d_in[27];
  const float* op_w    = (const float*)d_in[28];
  const float* op_b    = (const float*)d_in[29];
  float* out = (float*)d_out;
  float* ws = (float*)d_ws;

  // workspace layout (floats)
  float* feat1 = ws;                       // 4,718,592
  float* feat2 = ws + 4718592;             // 4,718,592 (y1 aliases start, dead before conv2)
  float* y1    = feat2;
  float* R     = ws + 9437184;             // scratch region
  bf16*  y2b   = (bf16*)R;                 // 18.87M bf16 (9.44M floats) — dead after conv2
  float* xp    = R;                        // 4,718,592 (overwrites y2b after it's dead)
  float* dwg   = R + 4718592;              // 4,718,592 — dead after offm gemm
  float* vagg  = dwg;                      // aliases dwg
  float* offm  = R + 9437184;              // 8,257,536 (stride 224)
  float* WTSf  = ws + 31555584;            // 41,568 floats
  bf16*  WTSb  = (bf16*)(WTSf + 41568);    // 217,088 bf16

  float* W1r  = WTSf;
  float* b1   = WTSf + 32768;
  float* b1b  = WTSf + 41088;
  float* b2   = WTSf + 41216;
  float* bom  = WTSf + 41344;
  bf16*  W2b  = WTSb;
  bf16*  Wipb = WTSb + 147456;
  bf16*  Womb = WTSb + 163840;
  bf16*  Wopb = WTSb + 192512;
  bf16*  W1bb = WTSb + 208896;

  prep_kernel<<<1011, 256, 0, stream>>>(
      conv_w, conv_g, conv_b, conv_rm, conv_rv,
      conv1_w, conv1_g, conv1_b, conv1_rm, conv1_rv,
      conv2_w, conv2_g, conv2_b, conv2_rm, conv2_rv,
      ip_w, op_w, off_w, m_w, off_b, m_b, WTSf, WTSb);

  conv1x1_kernel<<<288, 256, 0, stream>>>(x1, W1r, b1, 256, 2304, y1);
  upsample_kernel<<<18432, 256, 0, stream>>>(y1, feat1);

  c1x2_mfma_kernel<<<2304, 256, 0, stream>>>(x2, W1bb, b1b, y2b);
  conv2_mfma_kernel<<<576, 256, 0, stream>>>(y2b, W2b, b2, feat2);

  for (int d = 0; d < 2; ++d) {
    const float* feat = d ? feat2 : feat1;
    int choff = d ? 256 : 0;
    mm_bf16_kernel<<<dim3(576, 1), 256, 0, stream>>>(feat, Wipb, ip_b, 128, 128, 0, 0, 0, xp);
    dwln_kernel<<<4608, 256, 0, stream>>>(feat, dw_w, dw_b, ln_g, ln_b, dwg);
    mm_bf16_kernel<<<dim3(576, 2), 256, 0, stream>>>(dwg, Womb, bom, 224, 224, 0, 0, 0, offm);
    sample_kernel<<<4608, 256, 0, stream>>>(xp, offm, vagg);
    mm_bf16_kernel<<<dim3(576, 1), 256, 0, stream>>>(vagg, Wopb, op_b, 128, 0, 1, 1, choff, out);
  }

  copy_x0_kernel<<<4608, 256, 0, stream>>>((const float4*)x0, (float4*)out);
}

// Round 4
// 431.681 us; speedup vs baseline: 2.6206x; 1.1073x over previous
//
#include <hip/hip_runtime.h>
#include <cstdint>
#include <cstddef>

#define EPSV 1e-5f
#define NPIX 9216          // 96*96
#define LDA 136            // padded bf16 k-stride for 128-wide K chunks
#define LDK 72             // padded bf16 k-stride for 64-wide K chunks

typedef __bf16 bf16;
typedef __attribute__((ext_vector_type(8))) __bf16 bf16x8;
typedef __attribute__((ext_vector_type(4))) __bf16 bf16x4;
typedef __attribute__((ext_vector_type(4))) float  f32x4;

__device__ __forceinline__ float silu_f(float v) { return v / (1.f + __expf(-v)); }

// ---------------------------------------------------------------------------
// WTSf (float, 608): b1[128] | b1b[128] | b2[128] | bom[224]
// WTSb (bf16, 249856), all [co][ci]:
//   0       W1b  [128][256]  (x1 1x1, BN-folded)
//   32768   W1bb [128][64]   (x2 1x1, BN-folded)
//   40960   W2b  [9][128][128] (3x3 s2, BN-folded, k-major)
//   188416  Wipb [128][128]
//   204800  Womb [224][128]  (rows 216..223 zero)
//   233472  Wopb [128][128]
// ---------------------------------------------------------------------------
__global__ __launch_bounds__(256) void prep_kernel(
    const float* __restrict__ conv_w, const float* __restrict__ conv_g,
    const float* __restrict__ conv_b, const float* __restrict__ conv_rm, const float* __restrict__ conv_rv,
    const float* __restrict__ conv1_w, const float* __restrict__ conv1_g,
    const float* __restrict__ conv1_b, const float* __restrict__ conv1_rm, const float* __restrict__ conv1_rv,
    const float* __restrict__ conv2_w, const float* __restrict__ conv2_g,
    const float* __restrict__ conv2_bb, const float* __restrict__ conv2_rm, const float* __restrict__ conv2_rv,
    const float* __restrict__ ip_w, const float* __restrict__ op_w,
    const float* __restrict__ off_w, const float* __restrict__ m_w,
    const float* __restrict__ off_b, const float* __restrict__ m_b,
    float* __restrict__ WTSf, bf16* __restrict__ WTSb)
{
  int idx = blockIdx.x * 256 + threadIdx.x;
  if (idx < 608) {
    if (idx < 128) {
      int co = idx;
      float s = conv_g[co] * rsqrtf(conv_rv[co] + EPSV);
      WTSf[idx] = conv_b[co] - conv_rm[co] * s;
    } else if (idx < 256) {
      int co = idx - 128;
      float s = conv1_g[co] * rsqrtf(conv1_rv[co] + EPSV);
      WTSf[idx] = conv1_b[co] - conv1_rm[co] * s;
    } else if (idx < 384) {
      int co = idx - 256;
      float s = conv2_g[co] * rsqrtf(conv2_rv[co] + EPSV);
      WTSf[idx] = conv2_bb[co] - conv2_rm[co] * s;
    } else {
      int col = idx - 384;
      WTSf[idx] = (col < 144) ? off_b[col] : (col < 216 ? m_b[col - 144] : 0.f);
    }
  } else {
    int j = idx - 608;
    if (j < 32768) {
      int co = j >> 8, ci = j & 255;
      float s = conv_g[co] * rsqrtf(conv_rv[co] + EPSV);
      WTSb[j] = (bf16)(conv_w[co * 256 + ci] * s);
    } else if (j < 40960) {
      int r = j - 32768; int co = r >> 6, ci = r & 63;
      float s = conv1_g[co] * rsqrtf(conv1_rv[co] + EPSV);
      WTSb[j] = (bf16)(conv1_w[co * 64 + ci] * s);
    } else if (j < 188416) {
      int r = j - 40960; int kp = r >> 14; int rr = r & 16383;
      int co = rr >> 7, ci = rr & 127;
      float s = conv2_g[co] * rsqrtf(conv2_rv[co] + EPSV);
      WTSb[j] = (bf16)(conv2_w[(co * 128 + ci) * 9 + kp] * s);
    } else if (j < 204800) {
      int r = j - 188416; int co = r >> 7, ci = r & 127;
      WTSb[j] = (bf16)ip_w[co * 128 + ci];
    } else if (j < 233472) {
      int r = j - 204800; int co = r >> 7, ci = r & 127;
      float v = (co < 144) ? off_w[co * 128 + ci] : (co < 216 ? m_w[(co - 144) * 128 + ci] : 0.f);
      WTSb[j] = (bf16)v;
    } else if (j < 249856) {
      int r = j - 233472; int co = r >> 7, ci = r & 127;
      WTSb[j] = (bf16)op_w[co * 128 + ci];
    }
  }
}

// ---------------------------------------------------------------------------
// 1x1 conv via MFMA: NCHW fp32 (K ch) -> NHWC bf16 (128 ch) + BN + SiLU
// K chunked by 64. block 256 = 4 waves; tile 64 px x 128 co. LDS 27.6 KB.
// ---------------------------------------------------------------------------
__global__ __launch_bounds__(256) void c1x1_mfma_kernel(
    const float* __restrict__ x, const bf16* __restrict__ W,
    const float* __restrict__ bias, int K, int HW, bf16* __restrict__ outb)
{
  __shared__ bf16 As[64 * LDK];
  __shared__ bf16 Bs[128 * LDK];
  int m0 = blockIdx.x << 6;
  int t = threadIdx.x;
  int n = m0 / HW; int hw0 = m0 - n * HW;
  const float* xn = x + (size_t)n * K * HW;
  int wv = t >> 6, lane = t & 63;
  int lrow = lane & 15, q = lane >> 4;
  int n0 = wv * 32;
  f32x4 acc[4][2];
#pragma unroll
  for (int i = 0; i < 4; ++i)
#pragma unroll
    for (int j = 0; j < 2; ++j)
#pragma unroll
      for (int e = 0; e < 4; ++e) acc[i][j][e] = 0.f;

  for (int k0 = 0; k0 < K; k0 += 64) {
    if (k0) __syncthreads();
    // A: lanes over px (coalesced global), 4 ci per lane-task
    for (int i = t; i < 1024; i += 256) {
      int px = i & 63; int ci4 = (i >> 6) << 2;
      bf16x4 p;
#pragma unroll
      for (int j = 0; j < 4; ++j)
        p[j] = (bf16)xn[(size_t)(k0 + ci4 + j) * HW + hw0 + px];
      *(bf16x4*)&As[px * LDK + ci4] = p;
    }
    for (int i = t; i < 1024; i += 256) {
      int co = i >> 3; int k8 = (i & 7) << 3;
      *(bf16x8*)&Bs[co * LDK + k8] = *(const bf16x8*)&W[(size_t)co * K + k0 + k8];
    }
    __syncthreads();
#pragma unroll
    for (int ks = 0; ks < 2; ++ks) {
      int ko = ks * 32 + q * 8;
      bf16x8 bfr0 = *(const bf16x8*)&Bs[(n0 + lrow) * LDK + ko];
      bf16x8 bfr1 = *(const bf16x8*)&Bs[(n0 + 16 + lrow) * LDK + ko];
#pragma unroll
      for (int mi = 0; mi < 4; ++mi) {
        bf16x8 afr = *(const bf16x8*)&As[(mi * 16 + lrow) * LDK + ko];
        acc[mi][0] = __builtin_amdgcn_mfma_f32_16x16x32_bf16(afr, bfr0, acc[mi][0], 0, 0, 0);
        acc[mi][1] = __builtin_amdgcn_mfma_f32_16x16x32_bf16(afr, bfr1, acc[mi][1], 0, 0, 0);
      }
    }
  }
#pragma unroll
  for (int mi = 0; mi < 4; ++mi) {
#pragma unroll
    for (int nj = 0; nj < 2; ++nj) {
      int co = n0 + nj * 16 + lrow;
      float bb = bias[co];
#pragma unroll
      for (int r = 0; r < 4; ++r) {
        int m = m0 + mi * 16 + q * 4 + r;
        outb[(size_t)m * 128 + co] = (bf16)silu_f(acc[mi][nj][r] + bb);
      }
    }
  }
}

// ---------------------------------------------------------------------------
// bilinear 2x upsample, NHWC bf16 -> bf16 ; thread = 4 channels
// ---------------------------------------------------------------------------
__global__ __launch_bounds__(256) void upsample_kernel(
    const bf16* __restrict__ y1b, bf16* __restrict__ feat1b)
{
  int idx = blockIdx.x * 256 + threadIdx.x;   // 1,179,648 total
  int c4 = (idx & 31) << 2;
  int pw = idx >> 5;
  int ow = pw % 96; int t1 = pw / 96;
  int oh = t1 % 96; int n = t1 / 96;
  float sh = oh * 0.5f - 0.25f, sw = ow * 0.5f - 0.25f;
  float hf = floorf(sh), wf = floorf(sw);
  float fy = sh - hf, fx = sw - wf;
  int h0 = (int)hf, w0 = (int)wf;
  int h0c = max(h0, 0), h1c = min(h0 + 1, 47);
  int w0c = max(w0, 0), w1c = min(w0 + 1, 47);
  const bf16* yn = y1b + (size_t)n * 2304 * 128 + c4;
  bf16x4 v00 = *(const bf16x4*)&yn[(h0c * 48 + w0c) * 128];
  bf16x4 v01 = *(const bf16x4*)&yn[(h0c * 48 + w1c) * 128];
  bf16x4 v10 = *(const bf16x4*)&yn[(h1c * 48 + w0c) * 128];
  bf16x4 v11 = *(const bf16x4*)&yn[(h1c * 48 + w1c) * 128];
  bf16x4 o;
#pragma unroll
  for (int e = 0; e < 4; ++e) {
    float v = (1.f - fy) * ((1.f - fx) * (float)v00[e] + fx * (float)v01[e])
            + fy * ((1.f - fx) * (float)v10[e] + fx * (float)v11[e]);
    o[e] = (bf16)v;
  }
  *(bf16x4*)&feat1b[((size_t)n * NPIX + oh * 96 + ow) * 128 + c4] = o;
}

// ---------------------------------------------------------------------------
// conv2 via MFMA: 3x3 s2 p1 + BN + SiLU. y2b NHWC bf16 -> feat2b NHWC bf16.
// ---------------------------------------------------------------------------
__global__ __launch_bounds__(256) void conv2_mfma_kernel(
    const bf16* __restrict__ y2b, const bf16* __restrict__ W2b,
    const float* __restrict__ b2, bf16* __restrict__ feat2b)
{
  __shared__ bf16 As[64 * LDA];
  __shared__ bf16 Bs[128 * LDA];
  int m0 = blockIdx.x << 6;
  int t = threadIdx.x;
  int wv = t >> 6, lane = t & 63;
  int lrow = lane & 15, q = lane >> 4;
  int n0 = wv * 32;
  f32x4 acc[4][2];
#pragma unroll
  for (int i = 0; i < 4; ++i)
#pragma unroll
    for (int j = 0; j < 2; ++j)
#pragma unroll
      for (int e = 0; e < 4; ++e) acc[i][j][e] = 0.f;
  bf16x8 zv;
#pragma unroll
  for (int e = 0; e < 8; ++e) zv[e] = (bf16)0.f;

  for (int kp = 0; kp < 9; ++kp) {
    int kh = kp / 3, kw = kp - kh * 3;
    __syncthreads();
    for (int i = t; i < 1024; i += 256) {
      int row = i >> 4; int c8 = (i & 15) << 3;
      int m = m0 + row;
      int nimg = m / NPIX; int hw = m - nimg * NPIX;
      int oh = hw / 96, ow = hw - oh * 96;
      int ih = 2 * oh - 1 + kh, iw = 2 * ow - 1 + kw;
      bf16x8 v = zv;
      if ((unsigned)ih < 192u && (unsigned)iw < 192u)
        v = *(const bf16x8*)&y2b[(((size_t)nimg * 192 + ih) * 192 + iw) * 128 + c8];
      *(bf16x8*)&As[row * LDA + c8] = v;
    }
    const bf16* Wk = W2b + kp * 16384;
    for (int i = t; i < 2048; i += 256) {
      int nn = i >> 4; int k8 = (i & 15) << 3;
      *(bf16x8*)&Bs[nn * LDA + k8] = *(const bf16x8*)&Wk[nn * 128 + k8];
    }
    __syncthreads();
#pragma unroll
    for (int ks = 0; ks < 4; ++ks) {
      bf16x8 bfr0 = *(const bf16x8*)&Bs[(n0 + lrow) * LDA + ks * 32 + q * 8];
      bf16x8 bfr1 = *(const bf16x8*)&Bs[(n0 + 16 + lrow) * LDA + ks * 32 + q * 8];
#pragma unroll
      for (int mi = 0; mi < 4; ++mi) {
        bf16x8 afr = *(const bf16x8*)&As[(mi * 16 + lrow) * LDA + ks * 32 + q * 8];
        acc[mi][0] = __builtin_amdgcn_mfma_f32_16x16x32_bf16(afr, bfr0, acc[mi][0], 0, 0, 0);
        acc[mi][1] = __builtin_amdgcn_mfma_f32_16x16x32_bf16(afr, bfr1, acc[mi][1], 0, 0, 0);
      }
    }
  }
#pragma unroll
  for (int mi = 0; mi < 4; ++mi) {
#pragma unroll
    for (int nj = 0; nj < 2; ++nj) {
      int co = n0 + nj * 16 + lrow;
      float bb = b2[co];
#pragma unroll
      for (int r = 0; r < 4; ++r) {
        int m = m0 + mi * 16 + q * 4 + r;
        feat2b[(size_t)m * 128 + co] = (bf16)silu_f(acc[mi][nj][r] + bb);
      }
    }
  }
}

// ---------------------------------------------------------------------------
// Generic bf16 MFMA GEMM: A bf16 [M][128] @ W bf16 [Nc][128]^T + bias
// store_mode 0: fp32 out[m*ostride+col] ; 1: d_out NCHW + ReLU (dual-branch) ;
// 2: bf16 out[m*128+col]
// ---------------------------------------------------------------------------
__global__ __launch_bounds__(256) void mm_bf16_kernel(
    const bf16* __restrict__ A, const bf16* __restrict__ W,
    const float* __restrict__ bias, int Nc, int ostride, int act,
    int store_mode, void* __restrict__ outp)
{
  __shared__ bf16 As[64 * LDA];
  __shared__ bf16 Bs[128 * LDA];
  int m0 = blockIdx.x << 6;
  int nb = blockIdx.y << 7;
  int cols_here = Nc - nb; if (cols_here > 128) cols_here = 128;
  int t = threadIdx.x;
  for (int i = t; i < 1024; i += 256) {
    int row = i >> 4; int c8 = (i & 15) << 3;
    *(bf16x8*)&As[row * LDA + c8] = *(const bf16x8*)&A[(size_t)(m0 + row) * 128 + c8];
  }
  bf16x8 zv;
#pragma unroll
  for (int e = 0; e < 8; ++e) zv[e] = (bf16)0.f;
  for (int i = t; i < 2048; i += 256) {
    int n = i >> 4; int k8 = (i & 15) << 3;
    bf16x8 v = (n < cols_here) ? *(const bf16x8*)&W[(size_t)(nb + n) * 128 + k8] : zv;
    *(bf16x8*)&Bs[n * LDA + k8] = v;
  }
  __syncthreads();

  int wv = t >> 6, lane = t & 63;
  int lrow = lane & 15, q = lane >> 4;
  int n0 = wv * 32;
  f32x4 acc[4][2];
#pragma unroll
  for (int i = 0; i < 4; ++i)
#pragma unroll
    for (int j = 0; j < 2; ++j)
#pragma unroll
      for (int e = 0; e < 4; ++e) acc[i][j][e] = 0.f;

#pragma unroll
  for (int ks = 0; ks < 4; ++ks) {
    bf16x8 bfr0 = *(const bf16x8*)&Bs[(n0 + lrow) * LDA + ks * 32 + q * 8];
    bf16x8 bfr1 = *(const bf16x8*)&Bs[(n0 + 16 + lrow) * LDA + ks * 32 + q * 8];
#pragma unroll
    for (int mi = 0; mi < 4; ++mi) {
      bf16x8 afr = *(const bf16x8*)&As[(mi * 16 + lrow) * LDA + ks * 32 + q * 8];
      acc[mi][0] = __builtin_amdgcn_mfma_f32_16x16x32_bf16(afr, bfr0, acc[mi][0], 0, 0, 0);
      acc[mi][1] = __builtin_amdgcn_mfma_f32_16x16x32_bf16(afr, bfr1, acc[mi][1], 0, 0, 0);
    }
  }

  float* outf = (float*)outp;
  bf16*  outb = (bf16*)outp;
#pragma unroll
  for (int mi = 0; mi < 4; ++mi) {
#pragma unroll
    for (int nj = 0; nj < 2; ++nj) {
      int col = nb + n0 + nj * 16 + lrow;
      if (col >= Nc) continue;
      float bb = bias[col];
#pragma unroll
      for (int r = 0; r < 4; ++r) {
        int m = m0 + mi * 16 + q * 4 + r;
        float v = acc[mi][nj][r] + bb;
        if (act == 1) v = fmaxf(v, 0.f);
        if (store_mode == 0) {
          outf[(size_t)m * ostride + col] = v;
        } else if (store_mode == 2) {
          outb[(size_t)m * 128 + col] = (bf16)v;
        } else {
          int nn = m / NPIX; int hw = m - nn * NPIX;
          int img = nn & 3; int choff = (nn >= 4) ? 256 : 0;
          outf[((size_t)(img * 384 + choff + col)) * NPIX + hw] = v;
        }
      }
    }
  }
}

// ---------------------------------------------------------------------------
// Depthwise 3x3 + bias + LayerNorm + GELU(tanh), bf16 in/out
// block 256 = 16 px x 16 lanes; lane = 8 channels
// ---------------------------------------------------------------------------
__global__ __launch_bounds__(256) void dwln_kernel(
    const bf16* __restrict__ featb, const float* __restrict__ dw_w,
    const float* __restrict__ dw_b, const float* __restrict__ ln_g,
    const float* __restrict__ ln_b, bf16* __restrict__ dwgb)
{
  int t = threadIdx.x;
  int pxl = t >> 4;
  int c8 = (t & 15) << 3;
  int pixel = blockIdx.x * 16 + pxl;
  int n = pixel / NPIX; int hw = pixel - n * NPIX;
  int h = hw / 96; int w = hw - h * 96;
  const bf16* fn = featb + (size_t)n * NPIX * 128 + c8;
  float acc[8];
#pragma unroll
  for (int e = 0; e < 8; ++e) acc[e] = dw_b[c8 + e];
#pragma unroll
  for (int kh = 0; kh < 3; ++kh) {
    int hh = h + kh - 1;
    if ((unsigned)hh >= 96u) continue;
#pragma unroll
    for (int kw = 0; kw < 3; ++kw) {
      int ww = w + kw - 1;
      if ((unsigned)ww >= 96u) continue;
      bf16x8 v = *(const bf16x8*)&fn[(hh * 96 + ww) * 128];
      const float* wt = &dw_w[(kh * 3 + kw) * 128 + c8];
#pragma unroll
      for (int e = 0; e < 8; ++e) acc[e] += (float)v[e] * wt[e];
    }
  }
  float s = 0.f, qs = 0.f;
#pragma unroll
  for (int e = 0; e < 8; ++e) { s += acc[e]; qs += acc[e] * acc[e]; }
#pragma unroll
  for (int off = 8; off > 0; off >>= 1) {
    s  += __shfl_xor(s, off);
    qs += __shfl_xor(qs, off);
  }
  float mean = s * (1.f / 128.f);
  float var = qs * (1.f / 128.f) - mean * mean;
  float rstd = rsqrtf(var + EPSV);
  bf16x8 o;
#pragma unroll
  for (int e = 0; e < 8; ++e) {
    float xn = (acc[e] - mean) * rstd * ln_g[c8 + e] + ln_b[c8 + e];
    float z = 0.7978845608028654f * (xn + 0.044715f * xn * xn * xn);
    float th;
    if (z > 15.f) th = 1.f;
    else if (z < -15.f) th = -1.f;
    else { float e2 = __expf(2.f * z); th = (e2 - 1.f) / (e2 + 1.f); }
    o[e] = (bf16)(0.5f * xn * (1.f + th));
  }
  *(bf16x8*)&dwgb[(size_t)pixel * 128 + c8] = o;
}

// ---------------------------------------------------------------------------
// Deformable sampling, bf16x8 lanes: block 256 = 16 px x 8 g x 2 lanes
// ---------------------------------------------------------------------------
__global__ __launch_bounds__(256) void sample_kernel(
    const bf16* __restrict__ xpb, const float* __restrict__ offm,
    bf16* __restrict__ vaggb)
{
  __shared__ float S[16 * 224];
  int t = threadIdx.x;
  int bid = blockIdx.x;
  for (int i = t; i < 3584; i += 256) S[i] = offm[(size_t)bid * 3584 + i];
  __syncthreads();
  int pxl = t >> 4;
  int tid16 = t & 15;
  int g = tid16 >> 1;
  int c8 = (tid16 & 1) << 3;
  int pixel = bid * 16 + pxl;
  int n = pixel / NPIX; int hw = pixel - n * NPIX;
  int h = hw / 96; int w = hw - h * 96;
  const float* Sp = S + pxl * 224;
  float lg[9]; float mx = -1e30f;
#pragma unroll
  for (int p = 0; p < 9; ++p) { lg[p] = Sp[144 + g * 9 + p]; mx = fmaxf(mx, lg[p]); }
  float se = 0.f;
#pragma unroll
  for (int p = 0; p < 9; ++p) { lg[p] = __expf(lg[p] - mx); se += lg[p]; }
  float inv = 1.f / se;
  const bf16* xpn = xpb + (size_t)n * NPIX * 128 + g * 16 + c8;
  float acc[8];
#pragma unroll
  for (int e = 0; e < 8; ++e) acc[e] = 0.f;
#pragma unroll
  for (int p = 0; p < 9; ++p) {
    float dx = Sp[g * 18 + p * 2], dy = Sp[g * 18 + p * 2 + 1];
    float pyu = (float)(h + p / 3 - 1) + dy;
    float pxu = (float)(w + p % 3 - 1) + dx;
    float yf = floorf(pyu), xf = floorf(pxu);
    float wy = pyu - yf, wx = pxu - xf;
    int y0 = (int)yf, x0 = (int)xf;
    float ay0 = ((unsigned)y0 < 96u) ? (1.f - wy) : 0.f;
    float ay1 = ((unsigned)(y0 + 1) < 96u) ? wy : 0.f;
    float ax0 = ((unsigned)x0 < 96u) ? (1.f - wx) : 0.f;
    float ax1 = ((unsigned)(x0 + 1) < 96u) ? wx : 0.f;
    int y0c = min(max(y0, 0), 95), y1c = min(max(y0 + 1, 0), 95);
    int x0c = min(max(x0, 0), 95), x1c = min(max(x0 + 1, 0), 95);
    float w00 = ay0 * ax0, w01 = ay0 * ax1, w10 = ay1 * ax0, w11 = ay1 * ax1;
    bf16x8 v00 = *(const bf16x8*)&xpn[(y0c * 96 + x0c) * 128];
    bf16x8 v01 = *(const bf16x8*)&xpn[(y0c * 96 + x1c) * 128];
    bf16x8 v10 = *(const bf16x8*)&xpn[(y1c * 96 + x0c) * 128];
    bf16x8 v11 = *(const bf16x8*)&xpn[(y1c * 96 + x1c) * 128];
    float mp = lg[p] * inv;
#pragma unroll
    for (int e = 0; e < 8; ++e) {
      float sv = w00 * (float)v00[e] + w01 * (float)v01[e]
               + w10 * (float)v10[e] + w11 * (float)v11[e];
      acc[e] += mp * sv;
    }
  }
  bf16x8 o;
#pragma unroll
  for (int e = 0; e < 8; ++e) o[e] = (bf16)acc[e];
  *(bf16x8*)&vaggb[(size_t)pixel * 128 + g * 16 + c8] = o;
}

// ---------------------------------------------------------------------------
__global__ __launch_bounds__(256) void copy_x0_kernel(
    const float4* __restrict__ x0, float4* __restrict__ out)
{
  int idx = blockIdx.x * 256 + threadIdx.x;
  int n = idx / (128 * 2304);
  int r = idx - n * (128 * 2304);
  out[(size_t)(n * 384 + 128) * 2304 + r] = x0[(size_t)n * 128 * 2304 + r];
}

// ---------------------------------------------------------------------------
extern "C" void kernel_launch(void* const* d_in, const int* in_sizes, int n_in,
                              void* d_out, int out_size, void* d_ws, size_t ws_size,
                              hipStream_t stream)
{
  (void)in_sizes; (void)n_in; (void)out_size; (void)ws_size;
  const float* x0      = (const float*)d_in[0];
  const float* x1      = (const float*)d_in[1];
  const float* x2      = (const float*)d_in[2];
  const float* conv_w  = (const float*)d_in[3];
  const float* conv_g  = (const float*)d_in[4];
  const float* conv_b  = (const float*)d_in[5];
  const float* conv_rm = (const float*)d_in[6];
  const float* conv_rv = (const float*)d_in[7];
  const float* conv1_w = (const float*)d_in[8];
  const float* conv1_g = (const float*)d_in[9];
  const float* conv1_b = (const float*)d_in[10];
  const float* conv1_rm= (const float*)d_in[11];
  const float* conv1_rv= (const float*)d_in[12];
  const float* conv2_w = (const float*)d_in[13];
  const float* conv2_g = (const float*)d_in[14];
  const float* conv2_b = (const float*)d_in[15];
  const float* conv2_rm= (const float*)d_in[16];
  const float* conv2_rv= (const float*)d_in[17];
  const float* dw_w    = (const float*)d_in[18];
  const float* dw_b    = (const float*)d_in[19];
  const float* ln_g    = (const float*)d_in[20];
  const float* ln_b    = (const float*)d_in[21];
  const float* off_w   = (const float*)d_in[22];
  const float* off_b   = (const float*)d_in[23];
  const float* m_w     = (const float*)d_in[24];
  const float* m_b     = (const float*)d_in[25];
  const float* ip_w    = (const float*)d_in[26];
  const float* ip_b    = (const float*)d_in[27];
  const float* op_w    = (const float*)d_in[28];
  const float* op_b    = (const float*)d_in[29];
  float* out = (float*)d_out;
  char* WS = (char*)d_ws;

  // byte layout (125.5 MB total)
  bf16* featb  = (bf16*)WS;                      // 8 imgs x 9216 px x 128 ch
  bf16* feat1b = featb;
  bf16* feat2b = featb + 4718592;
  bf16* y2b    = (bf16*)(WS + 18874368);         // 37.7 MB, dead after conv2
  bf16* xpb    = (bf16*)(WS + 18874368);         // alias (written after conv2)
  bf16* dwgb   = (bf16*)(WS + 37748736);         // dead after om-gemm
  bf16* vaggb  = dwgb;                           // alias
  bf16* y1b    = (bf16*)(WS + 56623104);         // 2.36 MB, dead after upsample
  float* offm  = (float*)(WS + 58982400);        // 73728 x 224 fp32 = 66 MB
  float* WTSf  = (float*)(WS + 125042688);       // 608 floats
  bf16*  WTSb  = (bf16*)(WS + 125045120);        // 249856 bf16

  float* b1f  = WTSf;
  float* b1bf = WTSf + 128;
  float* b2f  = WTSf + 256;
  float* bomf = WTSf + 384;
  bf16* W1b  = WTSb;
  bf16* W1bb = WTSb + 32768;
  bf16* W2b  = WTSb + 40960;
  bf16* Wipb = WTSb + 188416;
  bf16* Womb = WTSb + 204800;
  bf16* Wopb = WTSb + 233472;

  prep_kernel<<<979, 256, 0, stream>>>(
      conv_w, conv_g, conv_b, conv_rm, conv_rv,
      conv1_w, conv1_g, conv1_b, conv1_rm, conv1_rv,
      conv2_w, conv2_g, conv2_b, conv2_rm, conv2_rv,
      ip_w, op_w, off_w, m_w, off_b, m_b, WTSf, WTSb);

  // x1 path: 1x1 conv (K=256) -> y1b ; upsample -> feat1b
  c1x1_mfma_kernel<<<144, 256, 0, stream>>>(x1, W1b, b1f, 256, 2304, y1b);
  upsample_kernel<<<4608, 256, 0, stream>>>(y1b, feat1b);

  // x2 path: 1x1 conv (K=64) -> y2b ; 3x3 s2 conv -> feat2b
  c1x1_mfma_kernel<<<2304, 256, 0, stream>>>(x2, W1bb, b1bf, 64, 36864, y2b);
  conv2_mfma_kernel<<<576, 256, 0, stream>>>(y2b, W2b, b2f, feat2b);

  // fused dual-branch DCNv3 (M = 73728)
  mm_bf16_kernel<<<dim3(1152, 1), 256, 0, stream>>>(featb, Wipb, ip_b, 128, 128, 0, 2, xpb);
  dwln_kernel<<<4608, 256, 0, stream>>>(featb, dw_w, dw_b, ln_g, ln_b, dwgb);
  mm_bf16_kernel<<<dim3(1152, 2), 256, 0, stream>>>(dwgb, Womb, bomf, 224, 224, 0, 0, offm);
  sample_kernel<<<4608, 256, 0, stream>>>(xpb, offm, vaggb);
  mm_bf16_kernel<<<dim3(1152, 1), 256, 0, stream>>>(vaggb, Wopb, op_b, 128, 0, 1, 1, out);

  copy_x0_kernel<<<4608, 256, 0, stream>>>((const float4*)x0, (float4*)out);
}